// Round 1
// baseline (4858.515 us; speedup 1.0000x reference)
//
#include <hip/hip_runtime.h>

#define N_NODES 50000
#define N_EDGES 800000
#define N_GRAPHS 256
#define DIN 126
#define H 128

// ---------------------------------------------------------------------------
// GEMM: O_m = act(X) @ W_m + b_m for m in {K,Q,V,skip}.  X: [M,Kd] row-major,
// W: [Kd,128] row-major, O: [M,128].  64x64 output tile per block, 4x4
// micro-tile per thread (256 threads).  X tile staged once (pad 130 kills the
// stride-128 bank conflict on A reads); W staged in two 64-row chunks to stay
// under the 64KB static LDS limit.
// ---------------------------------------------------------------------------
__global__ __launch_bounds__(256) void gemm4(
    const float* __restrict__ X, int M, int Kd, int relu_x,
    const float* __restrict__ W0, const float* __restrict__ b0, float* __restrict__ O0,
    const float* __restrict__ W1, const float* __restrict__ b1, float* __restrict__ O1,
    const float* __restrict__ W2, const float* __restrict__ b2, float* __restrict__ O2,
    const float* __restrict__ W3, const float* __restrict__ b3, float* __restrict__ O3)
{
    __shared__ float xs[64][130];   // 33280 B
    __shared__ float ws[64][64];    // 16384 B
    const int cb  = blockIdx.y;     // 0..7: (matrix, col-half)
    const int mtx = cb >> 1;
    const int coff = (cb & 1) * 64;
    const float* W; const float* bb; float* O;
    switch (mtx) {
        case 0:  W = W0; bb = b0; O = O0; break;
        case 1:  W = W1; bb = b1; O = O1; break;
        case 2:  W = W2; bb = b2; O = O2; break;
        default: W = W3; bb = b3; O = O3; break;
    }
    const int row0 = blockIdx.x * 64;
    const int tid  = threadIdx.x;

    // stage X tile: 64 rows x 128 k (zero-padded past Kd / past M)
    for (int i = tid; i < 64 * 128; i += 256) {
        const int r = i >> 7, k = i & 127;
        const int gr = row0 + r;
        float v = 0.f;
        if (gr < M && k < Kd) v = X[(size_t)gr * Kd + k];
        if (relu_x) v = fmaxf(v, 0.f);
        xs[r][k] = v;
    }

    const int tx = tid & 15, ty = tid >> 4;
    float acc[4][4] = {};

    for (int ko = 0; ko < 128; ko += 64) {
        __syncthreads();   // xs ready (first iter) / ws reads done (second)
        for (int i = tid; i < 64 * 64; i += 256) {
            const int k = i >> 6, c = i & 63;
            const int gk = ko + k;
            ws[k][c] = (gk < Kd) ? W[(size_t)gk * H + coff + c] : 0.f;
        }
        __syncthreads();
        #pragma unroll 8
        for (int k = 0; k < 64; ++k) {
            const float a0 = xs[ty * 4 + 0][ko + k];
            const float a1 = xs[ty * 4 + 1][ko + k];
            const float a2 = xs[ty * 4 + 2][ko + k];
            const float a3 = xs[ty * 4 + 3][ko + k];
            const float v0 = ws[k][tx * 4 + 0];
            const float v1 = ws[k][tx * 4 + 1];
            const float v2 = ws[k][tx * 4 + 2];
            const float v3 = ws[k][tx * 4 + 3];
            acc[0][0] += a0 * v0; acc[0][1] += a0 * v1; acc[0][2] += a0 * v2; acc[0][3] += a0 * v3;
            acc[1][0] += a1 * v0; acc[1][1] += a1 * v1; acc[1][2] += a1 * v2; acc[1][3] += a1 * v3;
            acc[2][0] += a2 * v0; acc[2][1] += a2 * v1; acc[2][2] += a2 * v2; acc[2][3] += a2 * v3;
            acc[3][0] += a3 * v0; acc[3][1] += a3 * v1; acc[3][2] += a3 * v2; acc[3][3] += a3 * v3;
        }
    }

    const float4 bias = *(const float4*)(bb + coff + tx * 4);
    #pragma unroll
    for (int i = 0; i < 4; ++i) {
        const int gr = row0 + ty * 4 + i;
        if (gr >= M) continue;
        float4 o;
        o.x = acc[i][0] + bias.x;
        o.y = acc[i][1] + bias.y;
        o.z = acc[i][2] + bias.z;
        o.w = acc[i][3] + bias.w;
        *(float4*)(O + (size_t)gr * H + coff + tx * 4) = o;
    }
}

// ---------------------------------------------------------------------------
// Edge phase: agg[dst] += sigmoid(K[dst]+Q[src]) * V[src].  32 lanes per edge,
// float4 per lane, 4 scalar f32 atomics per lane.
// ---------------------------------------------------------------------------
__global__ __launch_bounds__(256) void edge_kernel(
    const float* __restrict__ Kb, const float* __restrict__ Qb,
    const float* __restrict__ Vb, const int* __restrict__ ei,
    float* __restrict__ agg, int E)
{
    const int t = blockIdx.x * 256 + threadIdx.x;
    const int e = t >> 5;
    if (e >= E) return;
    const int q = (t & 31) * 4;
    const int s = ei[e];          // src = edge_index[0][e]
    const int d = ei[E + e];      // dst = edge_index[1][e]

    const float4 kv = *(const float4*)(Kb + (size_t)d * H + q);
    const float4 qv = *(const float4*)(Qb + (size_t)s * H + q);
    const float4 vv = *(const float4*)(Vb + (size_t)s * H + q);

    float4 m;
    m.x = vv.x / (1.f + __expf(-(kv.x + qv.x)));
    m.y = vv.y / (1.f + __expf(-(kv.y + qv.y)));
    m.z = vv.z / (1.f + __expf(-(kv.z + qv.z)));
    m.w = vv.w / (1.f + __expf(-(kv.w + qv.w)));

    float* o = agg + (size_t)d * H + q;
    atomicAdd(o + 0, m.x);
    atomicAdd(o + 1, m.y);
    atomicAdd(o + 2, m.z);
    atomicAdd(o + 3, m.w);
}

// ---------------------------------------------------------------------------
// Global add pool: hg[batch[n]] += h[n].  32 lanes per node row.
// ---------------------------------------------------------------------------
__global__ __launch_bounds__(256) void pool_kernel(
    const float* __restrict__ h, const int* __restrict__ batch,
    float* __restrict__ hg, int Nn)
{
    const int t = blockIdx.x * 256 + threadIdx.x;
    const int n = t >> 5;
    if (n >= Nn) return;
    const int q = (t & 31) * 4;
    const int g = batch[n];
    const float4 v = *(const float4*)(h + (size_t)n * H + q);
    float* o = hg + (size_t)g * H + q;
    atomicAdd(o + 0, v.x);
    atomicAdd(o + 1, v.y);
    atomicAdd(o + 2, v.z);
    atomicAdd(o + 3, v.w);
}

// ---------------------------------------------------------------------------
// Head MLP: out[g] = sigmoid( relu(hg[g] @ W4 + b4) @ W5 + b5 ).
// One block (64 threads = 64 hidden units) per graph; wave-reduce the final dot.
// ---------------------------------------------------------------------------
__global__ __launch_bounds__(64) void mlp_kernel(
    const float* __restrict__ hg,
    const float* __restrict__ W4, const float* __restrict__ b4,
    const float* __restrict__ W5, const float* __restrict__ b5,
    float* __restrict__ out)
{
    const int g = blockIdx.x;
    const int c = threadIdx.x;   // 0..63
    __shared__ float hrow[H];
    for (int k = c; k < H; k += 64) hrow[k] = hg[(size_t)g * H + k];
    __syncthreads();
    float s = b4[c];
    #pragma unroll 8
    for (int k = 0; k < H; ++k) s += hrow[k] * W4[(size_t)k * 64 + c];
    s = fmaxf(s, 0.f) * W5[c];
    #pragma unroll
    for (int off = 32; off > 0; off >>= 1) s += __shfl_down(s, off);
    if (c == 0) out[g] = 1.f / (1.f + __expf(-(s + b5[0])));
}

// ---------------------------------------------------------------------------
extern "C" void kernel_launch(void* const* d_in, const int* in_sizes, int n_in,
                              void* d_out, int out_size, void* d_ws, size_t ws_size,
                              hipStream_t stream)
{
    const float* x = (const float*)d_in[0];
    // d_in[1] = edge_attr (unused by the conv)
    const float *Wk[3], *bk[3], *Wq[3], *bq[3], *Wv[3], *bv[3], *Wsk[3], *bs[3];
    for (int l = 0; l < 3; ++l) {
        const int base = 2 + l * 8;
        Wk[l]  = (const float*)d_in[base + 0]; bk[l] = (const float*)d_in[base + 1];
        Wq[l]  = (const float*)d_in[base + 2]; bq[l] = (const float*)d_in[base + 3];
        Wv[l]  = (const float*)d_in[base + 4]; bv[l] = (const float*)d_in[base + 5];
        Wsk[l] = (const float*)d_in[base + 6]; bs[l] = (const float*)d_in[base + 7];
    }
    const float* W4 = (const float*)d_in[26];
    const float* b4 = (const float*)d_in[27];
    const float* W5 = (const float*)d_in[28];
    const float* b5 = (const float*)d_in[29];
    const int* ei    = (const int*)d_in[30];
    const int* batch = (const int*)d_in[31];
    float* out = (float*)d_out;

    const size_t NH = (size_t)N_NODES * H;
    float* Kbuf = (float*)d_ws;
    float* Qbuf = Kbuf + NH;
    float* Vbuf = Qbuf + NH;
    float* hA   = Vbuf + NH;
    float* hB   = hA + NH;
    float* hg   = hB + NH;
    // required ws: (5*NH + G*H) * 4 bytes ≈ 128.1 MB
    if (ws_size < (5 * NH + (size_t)N_GRAPHS * H) * sizeof(float)) return;

    dim3 ggrid((N_NODES + 63) / 64, 8);
    const int eblocks = (N_EDGES * 32 + 255) / 256;
    const int pblocks = (N_NODES * 32 + 255) / 256;

    // Layer 1 (input x, Kd=126, no input relu)
    gemm4<<<ggrid, 256, 0, stream>>>(x, N_NODES, DIN, 0,
        Wk[0], bk[0], Kbuf, Wq[0], bq[0], Qbuf, Wv[0], bv[0], Vbuf, Wsk[0], bs[0], hA);
    edge_kernel<<<eblocks, 256, 0, stream>>>(Kbuf, Qbuf, Vbuf, ei, hA, N_EDGES);

    // Layer 2 (relu of hA folded into GEMM's X staging)
    gemm4<<<ggrid, 256, 0, stream>>>(hA, N_NODES, H, 1,
        Wk[1], bk[1], Kbuf, Wq[1], bq[1], Qbuf, Wv[1], bv[1], Vbuf, Wsk[1], bs[1], hB);
    edge_kernel<<<eblocks, 256, 0, stream>>>(Kbuf, Qbuf, Vbuf, ei, hB, N_EDGES);

    // Layer 3 (relu of hB folded; no relu on output)
    gemm4<<<ggrid, 256, 0, stream>>>(hB, N_NODES, H, 1,
        Wk[2], bk[2], Kbuf, Wq[2], bq[2], Qbuf, Wv[2], bv[2], Vbuf, Wsk[2], bs[2], hA);
    edge_kernel<<<eblocks, 256, 0, stream>>>(Kbuf, Qbuf, Vbuf, ei, hA, N_EDGES);

    // Global add pool + head MLP
    hipMemsetAsync(hg, 0, (size_t)N_GRAPHS * H * sizeof(float), stream);
    pool_kernel<<<pblocks, 256, 0, stream>>>(hA, batch, hg, N_NODES);
    mlp_kernel<<<N_GRAPHS, 64, 0, stream>>>(hg, W4, b4, W5, b5, out);
}

// Round 2
// 1289.983 us; speedup vs baseline: 3.7663x; 3.7663x over previous
//
#include <hip/hip_runtime.h>

#define N_NODES 50000
#define N_EDGES 800000
#define N_GRAPHS 256
#define DIN 126
#define H 128

// ---------------------------------------------------------------------------
// GEMM: O_m = act(X) @ W_m + b_m for m in {K,Q,V,skip}. (unchanged from R1)
// ---------------------------------------------------------------------------
__global__ __launch_bounds__(256) void gemm4(
    const float* __restrict__ X, int M, int Kd, int relu_x,
    const float* __restrict__ W0, const float* __restrict__ b0, float* __restrict__ O0,
    const float* __restrict__ W1, const float* __restrict__ b1, float* __restrict__ O1,
    const float* __restrict__ W2, const float* __restrict__ b2, float* __restrict__ O2,
    const float* __restrict__ W3, const float* __restrict__ b3, float* __restrict__ O3)
{
    __shared__ float xs[64][130];
    __shared__ float ws[64][64];
    const int cb  = blockIdx.y;
    const int mtx = cb >> 1;
    const int coff = (cb & 1) * 64;
    const float* W; const float* bb; float* O;
    switch (mtx) {
        case 0:  W = W0; bb = b0; O = O0; break;
        case 1:  W = W1; bb = b1; O = O1; break;
        case 2:  W = W2; bb = b2; O = O2; break;
        default: W = W3; bb = b3; O = O3; break;
    }
    const int row0 = blockIdx.x * 64;
    const int tid  = threadIdx.x;

    for (int i = tid; i < 64 * 128; i += 256) {
        const int r = i >> 7, k = i & 127;
        const int gr = row0 + r;
        float v = 0.f;
        if (gr < M && k < Kd) v = X[(size_t)gr * Kd + k];
        if (relu_x) v = fmaxf(v, 0.f);
        xs[r][k] = v;
    }

    const int tx = tid & 15, ty = tid >> 4;
    float acc[4][4] = {};

    for (int ko = 0; ko < 128; ko += 64) {
        __syncthreads();
        for (int i = tid; i < 64 * 64; i += 256) {
            const int k = i >> 6, c = i & 63;
            const int gk = ko + k;
            ws[k][c] = (gk < Kd) ? W[(size_t)gk * H + coff + c] : 0.f;
        }
        __syncthreads();
        #pragma unroll 8
        for (int k = 0; k < 64; ++k) {
            const float a0 = xs[ty * 4 + 0][ko + k];
            const float a1 = xs[ty * 4 + 1][ko + k];
            const float a2 = xs[ty * 4 + 2][ko + k];
            const float a3 = xs[ty * 4 + 3][ko + k];
            const float v0 = ws[k][tx * 4 + 0];
            const float v1 = ws[k][tx * 4 + 1];
            const float v2 = ws[k][tx * 4 + 2];
            const float v3 = ws[k][tx * 4 + 3];
            acc[0][0] += a0 * v0; acc[0][1] += a0 * v1; acc[0][2] += a0 * v2; acc[0][3] += a0 * v3;
            acc[1][0] += a1 * v0; acc[1][1] += a1 * v1; acc[1][2] += a1 * v2; acc[1][3] += a1 * v3;
            acc[2][0] += a2 * v0; acc[2][1] += a2 * v1; acc[2][2] += a2 * v2; acc[2][3] += a2 * v3;
            acc[3][0] += a3 * v0; acc[3][1] += a3 * v1; acc[3][2] += a3 * v2; acc[3][3] += a3 * v3;
        }
    }

    const float4 bias = *(const float4*)(bb + coff + tx * 4);
    #pragma unroll
    for (int i = 0; i < 4; ++i) {
        const int gr = row0 + ty * 4 + i;
        if (gr >= M) continue;
        float4 o;
        o.x = acc[i][0] + bias.x;
        o.y = acc[i][1] + bias.y;
        o.z = acc[i][2] + bias.z;
        o.w = acc[i][3] + bias.w;
        *(float4*)(O + (size_t)gr * H + coff + tx * 4) = o;
    }
}

// ---------------------------------------------------------------------------
// CSR build: histogram of dst, single-block scan, atomic scatter of src ids.
// ---------------------------------------------------------------------------
__global__ __launch_bounds__(256) void hist_kernel(const int* __restrict__ ei,
                                                   int* __restrict__ cnt, int E)
{
    const int e = blockIdx.x * 256 + threadIdx.x;
    if (e < E) atomicAdd(&cnt[ei[E + e]], 1);
}

// single block, 1024 threads; cnt is read then overwritten with the running
// offset (cur aliases cnt); off[] gets the exclusive prefix (N+1 entries).
__global__ __launch_bounds__(1024) void scan_kernel(int* __restrict__ cnt,
                                                    int* __restrict__ off, int Nn)
{
    __shared__ int part[1024];
    const int t = threadIdx.x;
    const int CH = (Nn + 1023) / 1024;
    const int base = t * CH;
    int s = 0;
    for (int i = 0; i < CH; ++i) {
        const int idx = base + i;
        if (idx < Nn) s += cnt[idx];
    }
    part[t] = s;
    __syncthreads();
    for (int d = 1; d < 1024; d <<= 1) {
        const int v = (t >= d) ? part[t - d] : 0;
        __syncthreads();
        part[t] += v;
        __syncthreads();
    }
    int run = (t == 0) ? 0 : part[t - 1];
    for (int i = 0; i < CH; ++i) {
        const int idx = base + i;
        if (idx < Nn) {
            const int c = cnt[idx];
            off[idx] = run;
            cnt[idx] = run;   // becomes the scatter cursor
            run += c;
        }
    }
    if (t == 1023) off[Nn] = run;
}

__global__ __launch_bounds__(256) void scatter_kernel(const int* __restrict__ ei,
                                                      int* __restrict__ cur,
                                                      int* __restrict__ csr_src, int E)
{
    const int e = blockIdx.x * 256 + threadIdx.x;
    if (e >= E) return;
    const int s = ei[e];
    const int d = ei[E + e];
    const int pos = atomicAdd(&cur[d], 1);
    csr_src[pos] = s;
}

// ---------------------------------------------------------------------------
// CSR aggregation: hOut[i] += sum_{j in in(i)} sigmoid(K[i]+Q[j]) * V[j].
// One wave (64 lanes, float2/lane) per destination node; K in regs; plain
// coalesced stores (no atomics). src ids loaded once per wave, shfl-broadcast.
// ---------------------------------------------------------------------------
__global__ __launch_bounds__(256) void agg_csr(
    const float* __restrict__ Kb, const float* __restrict__ Qb,
    const float* __restrict__ Vb, const int* __restrict__ off,
    const int* __restrict__ csr_src, float* __restrict__ hOut, int Nn)
{
    const int node = blockIdx.x * 4 + (threadIdx.x >> 6);
    if (node >= Nn) return;
    const int lane = threadIdx.x & 63;
    const int q = lane * 2;

    const float2 kv = *(const float2*)(Kb + (size_t)node * H + q);
    float2 acc = *(const float2*)(hOut + (size_t)node * H + q);

    const int begin = off[node], end = off[node + 1];
    for (int j0 = begin; j0 < end; j0 += 64) {
        const int nrem = end - j0;
        const int nk = nrem < 64 ? nrem : 64;
        const int sv = (lane < nk) ? csr_src[j0 + lane] : 0;
        #pragma unroll 4
        for (int k = 0; k < nk; ++k) {
            const int s = __shfl(sv, k);
            const float2 qv = *(const float2*)(Qb + (size_t)s * H + q);
            const float2 vv = *(const float2*)(Vb + (size_t)s * H + q);
            acc.x += vv.x / (1.f + __expf(-(kv.x + qv.x)));
            acc.y += vv.y / (1.f + __expf(-(kv.y + qv.y)));
        }
    }
    *(float2*)(hOut + (size_t)node * H + q) = acc;
}

// ---------------------------------------------------------------------------
// Graph segment starts from sorted batch: gstart[g] = first node of graph g;
// gstart[G] = N.  Handles empty graphs.
// ---------------------------------------------------------------------------
__global__ __launch_bounds__(256) void gstart_kernel(const int* __restrict__ batch,
                                                     int* __restrict__ gstart, int Nn)
{
    const int n = blockIdx.x * 256 + threadIdx.x;
    if (n >= Nn) return;
    const int b = batch[n];
    const int bp = (n == 0) ? -1 : batch[n - 1];
    for (int g = bp + 1; g <= b; ++g) gstart[g] = n;
    if (n == Nn - 1)
        for (int g = b + 1; g <= N_GRAPHS; ++g) gstart[g] = Nn;
}

// Pool: one block (128 threads = one dim each) per graph; sequential node sum.
__global__ __launch_bounds__(128) void pool_seg(const float* __restrict__ h,
                                                const int* __restrict__ gstart,
                                                float* __restrict__ hg)
{
    const int g = blockIdx.x;
    const int t = threadIdx.x;
    const int b0 = gstart[g], b1 = gstart[g + 1];
    float acc = 0.f;
    for (int n = b0; n < b1; ++n) acc += h[(size_t)n * H + t];
    hg[(size_t)g * H + t] = acc;
}

// ---------------------------------------------------------------------------
// Head MLP (unchanged).
// ---------------------------------------------------------------------------
__global__ __launch_bounds__(64) void mlp_kernel(
    const float* __restrict__ hg,
    const float* __restrict__ W4, const float* __restrict__ b4,
    const float* __restrict__ W5, const float* __restrict__ b5,
    float* __restrict__ out)
{
    const int g = blockIdx.x;
    const int c = threadIdx.x;
    __shared__ float hrow[H];
    for (int k = c; k < H; k += 64) hrow[k] = hg[(size_t)g * H + k];
    __syncthreads();
    float s = b4[c];
    #pragma unroll 8
    for (int k = 0; k < H; ++k) s += hrow[k] * W4[(size_t)k * 64 + c];
    s = fmaxf(s, 0.f) * W5[c];
    #pragma unroll
    for (int off = 32; off > 0; off >>= 1) s += __shfl_down(s, off);
    if (c == 0) out[g] = 1.f / (1.f + __expf(-(s + b5[0])));
}

// ---------------------------------------------------------------------------
extern "C" void kernel_launch(void* const* d_in, const int* in_sizes, int n_in,
                              void* d_out, int out_size, void* d_ws, size_t ws_size,
                              hipStream_t stream)
{
    const float* x = (const float*)d_in[0];
    const float *Wk[3], *bk[3], *Wq[3], *bq[3], *Wv[3], *bv[3], *Wsk[3], *bs[3];
    for (int l = 0; l < 3; ++l) {
        const int base = 2 + l * 8;
        Wk[l]  = (const float*)d_in[base + 0]; bk[l] = (const float*)d_in[base + 1];
        Wq[l]  = (const float*)d_in[base + 2]; bq[l] = (const float*)d_in[base + 3];
        Wv[l]  = (const float*)d_in[base + 4]; bv[l] = (const float*)d_in[base + 5];
        Wsk[l] = (const float*)d_in[base + 6]; bs[l] = (const float*)d_in[base + 7];
    }
    const float* W4 = (const float*)d_in[26];
    const float* b4 = (const float*)d_in[27];
    const float* W5 = (const float*)d_in[28];
    const float* b5 = (const float*)d_in[29];
    const int* ei    = (const int*)d_in[30];
    const int* batch = (const int*)d_in[31];
    float* out = (float*)d_out;

    const size_t NH = (size_t)N_NODES * H;
    float* Kbuf = (float*)d_ws;
    float* Qbuf = Kbuf + NH;
    float* Vbuf = Qbuf + NH;
    float* hA   = Vbuf + NH;
    float* hB   = hA + NH;
    float* hg   = hB + NH;                       // G*H floats
    int*   off  = (int*)(hg + (size_t)N_GRAPHS * H);  // N+1
    int*   cnt  = off + (N_NODES + 1);           // N (doubles as scatter cursor)
    int*   csr  = cnt + N_NODES;                 // E
    int*   gst  = csr + N_EDGES;                 // G+1
    const size_t need = (5 * NH + (size_t)N_GRAPHS * H) * sizeof(float)
                      + (size_t)(2 * N_NODES + 1 + N_EDGES + N_GRAPHS + 1) * sizeof(int);
    if (ws_size < need) return;

    dim3 ggrid((N_NODES + 63) / 64, 8);
    const int eblk = (N_EDGES + 255) / 256;
    const int ablk = (N_NODES + 3) / 4;
    const int nblk = (N_NODES + 255) / 256;

    // ---- CSR + graph-segment build (once per call, reused by all 3 layers)
    hipMemsetAsync(cnt, 0, N_NODES * sizeof(int), stream);
    hist_kernel<<<eblk, 256, 0, stream>>>(ei, cnt, N_EDGES);
    scan_kernel<<<1, 1024, 0, stream>>>(cnt, off, N_NODES);
    scatter_kernel<<<eblk, 256, 0, stream>>>(ei, cnt, csr, N_EDGES);
    gstart_kernel<<<nblk, 256, 0, stream>>>(batch, gst, N_NODES);

    // ---- Layer 1
    gemm4<<<ggrid, 256, 0, stream>>>(x, N_NODES, DIN, 0,
        Wk[0], bk[0], Kbuf, Wq[0], bq[0], Qbuf, Wv[0], bv[0], Vbuf, Wsk[0], bs[0], hA);
    agg_csr<<<ablk, 256, 0, stream>>>(Kbuf, Qbuf, Vbuf, off, csr, hA, N_NODES);

    // ---- Layer 2
    gemm4<<<ggrid, 256, 0, stream>>>(hA, N_NODES, H, 1,
        Wk[1], bk[1], Kbuf, Wq[1], bq[1], Qbuf, Wv[1], bv[1], Vbuf, Wsk[1], bs[1], hB);
    agg_csr<<<ablk, 256, 0, stream>>>(Kbuf, Qbuf, Vbuf, off, csr, hB, N_NODES);

    // ---- Layer 3
    gemm4<<<ggrid, 256, 0, stream>>>(hB, N_NODES, H, 1,
        Wk[2], bk[2], Kbuf, Wq[2], bq[2], Qbuf, Wv[2], bv[2], Vbuf, Wsk[2], bs[2], hA);
    agg_csr<<<ablk, 256, 0, stream>>>(Kbuf, Qbuf, Vbuf, off, csr, hA, N_NODES);

    // ---- Pool + MLP
    pool_seg<<<N_GRAPHS, 128, 0, stream>>>(hA, gst, hg);
    mlp_kernel<<<N_GRAPHS, 64, 0, stream>>>(hg, W4, b4, W5, b5, out);
}

// Round 3
// 856.738 us; speedup vs baseline: 5.6709x; 1.5057x over previous
//
#include <hip/hip_runtime.h>

#define N_NODES 50000
#define N_EDGES 800000
#define N_GRAPHS 256
#define DIN 126
#define H 128
#define MP 50048   // N_NODES padded to 128

typedef __attribute__((ext_vector_type(8))) short short8v;
typedef __attribute__((ext_vector_type(4))) float f32x4;

// ---------------------------------------------------------------------------
// fp32 -> bf16 hi/lo split helpers (RNE)
// ---------------------------------------------------------------------------
__device__ __forceinline__ unsigned short f2bf(float f) {
    const unsigned u = __float_as_uint(f);
    return (unsigned short)((u + 0x7FFFu + ((u >> 16) & 1u)) >> 16);
}
__device__ __forceinline__ float bf2f(unsigned short s) {
    return __uint_as_float(((unsigned)s) << 16);
}

// ---------------------------------------------------------------------------
// A conversion: X fp32 [M,Kd] (+optional relu) -> Ah,Al bf16 [MP][128]
// (zero-padded in k past Kd and rows past M). One thread per (row, 8 k).
// ---------------------------------------------------------------------------
__global__ __launch_bounds__(256) void conv_A(const float* __restrict__ X, int M, int Kd,
                                              int relu, short* __restrict__ Ah,
                                              short* __restrict__ Al)
{
    const int t = blockIdx.x * 256 + threadIdx.x;
    const int row = t >> 4;
    if (row >= MP) return;
    const int k0 = (t & 15) * 8;
    short8v hv, lv;
    #pragma unroll
    for (int j = 0; j < 8; ++j) {
        const int k = k0 + j;
        float v = 0.f;
        if (row < M && k < Kd) v = X[(size_t)row * Kd + k];
        if (relu) v = fmaxf(v, 0.f);
        const unsigned short hb = f2bf(v);
        const float lo = v - bf2f(hb);
        hv[j] = (short)hb;
        lv[j] = (short)f2bf(lo);
    }
    const size_t o = (size_t)row * 128 + k0;
    *(short8v*)&Ah[o] = hv;
    *(short8v*)&Al[o] = lv;
}

// ---------------------------------------------------------------------------
// W conversion (one layer): four [Kd,128] fp32 -> transposed Wth/Wtl bf16
// [512 n][128 k] (n = mtx*128 + col), zero-padded past Kd.
// ---------------------------------------------------------------------------
__global__ __launch_bounds__(256) void conv_W(
    const float* __restrict__ W0, const float* __restrict__ W1,
    const float* __restrict__ W2, const float* __restrict__ W3,
    int Kd, short* __restrict__ Wth, short* __restrict__ Wtl)
{
    const int t = blockIdx.x * 256 + threadIdx.x;
    if (t >= 512 * 128) return;
    const int n = t >> 7, k = t & 127;
    const int mtx = n >> 7, cc = n & 127;
    const float* W = mtx == 0 ? W0 : mtx == 1 ? W1 : mtx == 2 ? W2 : W3;
    const float v = (k < Kd) ? W[(size_t)k * 128 + cc] : 0.f;
    const unsigned short hb = f2bf(v);
    Wth[t] = (short)hb;
    Wtl[t] = (short)f2bf(v - bf2f(hb));
}

// ---------------------------------------------------------------------------
// MFMA GEMM (hi/lo split): O[mtx] = A @ W[mtx] + b[mtx], fp32-class accuracy.
// Block: 128 rows x 128 cols (blockIdx.y = mtx), 4 waves of 64x64,
// 16x16x32 bf16 MFMA, 3 products per fragment (AhWh + AhWl + AlWh).
// LDS: 4 tiles [128][64] bf16, XOR-swizzled (slot ^= row&7) on write AND read.
// ---------------------------------------------------------------------------
__global__ __launch_bounds__(256) void gemm_mfma(
    const short* __restrict__ Ah, const short* __restrict__ Al,
    const short* __restrict__ Wth, const short* __restrict__ Wtl,
    const float* __restrict__ bias0, const float* __restrict__ bias1,
    const float* __restrict__ bias2, const float* __restrict__ bias3,
    float* __restrict__ O0, float* __restrict__ O1,
    float* __restrict__ O2, float* __restrict__ O3, int M)
{
    __shared__ short lds[4][8192];  // Ah, Al, Wh, Wl tiles: 16KB each = 64KB
    const int t = threadIdx.x;
    const int l = t & 63, w = t >> 6;
    const int wr = w >> 1, wc = w & 1;
    const int mtx = blockIdx.y;
    const int row0 = blockIdx.x * 128;
    const int ncol0 = mtx * 128;

    f32x4 acc[4][4] = {};

    for (int c = 0; c < 2; ++c) {
        __syncthreads();   // protect previous iteration's LDS reads
        // ---- stage 4 tiles [128 rows][64 k] bf16, swizzled writes
        #pragma unroll
        for (int i = 0; i < 4; ++i) {
            const int li = i * 256 + t;          // 16B granule id (0..1023)
            const int r = li >> 3, k16 = li & 7;
            const int lo = r * 64 + ((k16 ^ (r & 7)) * 8);   // short offset
            const size_t ga = (size_t)(row0 + r) * 128 + c * 64 + k16 * 8;
            const size_t gw = (size_t)(ncol0 + r) * 128 + c * 64 + k16 * 8;
            *(short8v*)&lds[0][lo] = *(const short8v*)&Ah[ga];
            *(short8v*)&lds[1][lo] = *(const short8v*)&Al[ga];
            *(short8v*)&lds[2][lo] = *(const short8v*)&Wth[gw];
            *(short8v*)&lds[3][lo] = *(const short8v*)&Wtl[gw];
        }
        __syncthreads();
        // ---- 2 MFMA K-steps (K=32 each) over this 64-k chunk
        #pragma unroll
        for (int s = 0; s < 2; ++s) {
            short8v ah[4], al[4], wh[4], wl[4];
            const int kg = s * 4 + (l >> 4);
            #pragma unroll
            for (int m = 0; m < 4; ++m) {
                const int ar = wr * 64 + m * 16 + (l & 15);
                const int ao = ar * 64 + ((kg ^ (ar & 7)) * 8);
                ah[m] = *(const short8v*)&lds[0][ao];
                al[m] = *(const short8v*)&lds[1][ao];
                const int br = wc * 64 + m * 16 + (l & 15);
                const int bo = br * 64 + ((kg ^ (br & 7)) * 8);
                wh[m] = *(const short8v*)&lds[2][bo];
                wl[m] = *(const short8v*)&lds[3][bo];
            }
            #pragma unroll
            for (int m = 0; m < 4; ++m)
                #pragma unroll
                for (int n = 0; n < 4; ++n) {
                    acc[m][n] = __builtin_amdgcn_mfma_f32_16x16x32_bf16(ah[m], wh[n], acc[m][n], 0, 0, 0);
                    acc[m][n] = __builtin_amdgcn_mfma_f32_16x16x32_bf16(ah[m], wl[n], acc[m][n], 0, 0, 0);
                    acc[m][n] = __builtin_amdgcn_mfma_f32_16x16x32_bf16(al[m], wh[n], acc[m][n], 0, 0, 0);
                }
        }
    }

    // ---- epilogue: C layout col=lane&15, row=(lane>>4)*4+reg (m89-verified)
    const float* bias = mtx == 0 ? bias0 : mtx == 1 ? bias1 : mtx == 2 ? bias2 : bias3;
    float*       O    = mtx == 0 ? O0    : mtx == 1 ? O1    : mtx == 2 ? O2    : O3;
    #pragma unroll
    for (int n = 0; n < 4; ++n) {
        const int col = wc * 64 + n * 16 + (l & 15);
        const float bv = bias[col];
        #pragma unroll
        for (int m = 0; m < 4; ++m) {
            const int rb = row0 + wr * 64 + m * 16 + ((l >> 4) * 4);
            #pragma unroll
            for (int j = 0; j < 4; ++j) {
                const int r = rb + j;
                if (r < M) O[(size_t)r * 128 + col] = acc[m][n][j] + bv;
            }
        }
    }
}

// ---------------------------------------------------------------------------
// CSR build (unchanged from R2)
// ---------------------------------------------------------------------------
__global__ __launch_bounds__(256) void hist_kernel(const int* __restrict__ ei,
                                                   int* __restrict__ cnt, int E)
{
    const int e = blockIdx.x * 256 + threadIdx.x;
    if (e < E) atomicAdd(&cnt[ei[E + e]], 1);
}

__global__ __launch_bounds__(1024) void scan_kernel(int* __restrict__ cnt,
                                                    int* __restrict__ off, int Nn)
{
    __shared__ int part[1024];
    const int t = threadIdx.x;
    const int CH = (Nn + 1023) / 1024;
    const int base = t * CH;
    int s = 0;
    for (int i = 0; i < CH; ++i) {
        const int idx = base + i;
        if (idx < Nn) s += cnt[idx];
    }
    part[t] = s;
    __syncthreads();
    for (int d = 1; d < 1024; d <<= 1) {
        const int v = (t >= d) ? part[t - d] : 0;
        __syncthreads();
        part[t] += v;
        __syncthreads();
    }
    int run = (t == 0) ? 0 : part[t - 1];
    for (int i = 0; i < CH; ++i) {
        const int idx = base + i;
        if (idx < Nn) {
            const int c = cnt[idx];
            off[idx] = run;
            cnt[idx] = run;
            run += c;
        }
    }
    if (t == 1023) off[Nn] = run;
}

__global__ __launch_bounds__(256) void scatter_kernel(const int* __restrict__ ei,
                                                      int* __restrict__ cur,
                                                      int* __restrict__ csr_src, int E)
{
    const int e = blockIdx.x * 256 + threadIdx.x;
    if (e >= E) return;
    const int s = ei[e];
    const int d = ei[E + e];
    const int pos = atomicAdd(&cur[d], 1);
    csr_src[pos] = s;
}

// ---------------------------------------------------------------------------
// CSR aggregation (unchanged from R2)
// ---------------------------------------------------------------------------
__global__ __launch_bounds__(256) void agg_csr(
    const float* __restrict__ Kb, const float* __restrict__ Qb,
    const float* __restrict__ Vb, const int* __restrict__ off,
    const int* __restrict__ csr_src, float* __restrict__ hOut, int Nn)
{
    const int node = blockIdx.x * 4 + (threadIdx.x >> 6);
    if (node >= Nn) return;
    const int lane = threadIdx.x & 63;
    const int q = lane * 2;

    const float2 kv = *(const float2*)(Kb + (size_t)node * H + q);
    float2 acc = *(const float2*)(hOut + (size_t)node * H + q);

    const int begin = off[node], end = off[node + 1];
    for (int j0 = begin; j0 < end; j0 += 64) {
        const int nrem = end - j0;
        const int nk = nrem < 64 ? nrem : 64;
        const int sv = (lane < nk) ? csr_src[j0 + lane] : 0;
        #pragma unroll 4
        for (int k = 0; k < nk; ++k) {
            const int s = __shfl(sv, k);
            const float2 qv = *(const float2*)(Qb + (size_t)s * H + q);
            const float2 vv = *(const float2*)(Vb + (size_t)s * H + q);
            acc.x += vv.x / (1.f + __expf(-(kv.x + qv.x)));
            acc.y += vv.y / (1.f + __expf(-(kv.y + qv.y)));
        }
    }
    *(float2*)(hOut + (size_t)node * H + q) = acc;
}

// ---------------------------------------------------------------------------
// Pool + MLP (unchanged from R2)
// ---------------------------------------------------------------------------
__global__ __launch_bounds__(256) void gstart_kernel(const int* __restrict__ batch,
                                                     int* __restrict__ gstart, int Nn)
{
    const int n = blockIdx.x * 256 + threadIdx.x;
    if (n >= Nn) return;
    const int b = batch[n];
    const int bp = (n == 0) ? -1 : batch[n - 1];
    for (int g = bp + 1; g <= b; ++g) gstart[g] = n;
    if (n == Nn - 1)
        for (int g = b + 1; g <= N_GRAPHS; ++g) gstart[g] = Nn;
}

__global__ __launch_bounds__(128) void pool_seg(const float* __restrict__ h,
                                                const int* __restrict__ gstart,
                                                float* __restrict__ hg)
{
    const int g = blockIdx.x;
    const int t = threadIdx.x;
    const int b0 = gstart[g], b1 = gstart[g + 1];
    float acc = 0.f;
    for (int n = b0; n < b1; ++n) acc += h[(size_t)n * H + t];
    hg[(size_t)g * H + t] = acc;
}

__global__ __launch_bounds__(64) void mlp_kernel(
    const float* __restrict__ hg,
    const float* __restrict__ W4, const float* __restrict__ b4,
    const float* __restrict__ W5, const float* __restrict__ b5,
    float* __restrict__ out)
{
    const int g = blockIdx.x;
    const int c = threadIdx.x;
    __shared__ float hrow[H];
    for (int k = c; k < H; k += 64) hrow[k] = hg[(size_t)g * H + k];
    __syncthreads();
    float s = b4[c];
    #pragma unroll 8
    for (int k = 0; k < H; ++k) s += hrow[k] * W4[(size_t)k * 64 + c];
    s = fmaxf(s, 0.f) * W5[c];
    #pragma unroll
    for (int off = 32; off > 0; off >>= 1) s += __shfl_down(s, off);
    if (c == 0) out[g] = 1.f / (1.f + __expf(-(s + b5[0])));
}

// ---------------------------------------------------------------------------
extern "C" void kernel_launch(void* const* d_in, const int* in_sizes, int n_in,
                              void* d_out, int out_size, void* d_ws, size_t ws_size,
                              hipStream_t stream)
{
    const float* x = (const float*)d_in[0];
    const float *Wk[3], *bk[3], *Wq[3], *bq[3], *Wv[3], *bv[3], *Wsk[3], *bs[3];
    for (int l = 0; l < 3; ++l) {
        const int base = 2 + l * 8;
        Wk[l]  = (const float*)d_in[base + 0]; bk[l] = (const float*)d_in[base + 1];
        Wq[l]  = (const float*)d_in[base + 2]; bq[l] = (const float*)d_in[base + 3];
        Wv[l]  = (const float*)d_in[base + 4]; bv[l] = (const float*)d_in[base + 5];
        Wsk[l] = (const float*)d_in[base + 6]; bs[l] = (const float*)d_in[base + 7];
    }
    const float* W4 = (const float*)d_in[26];
    const float* b4 = (const float*)d_in[27];
    const float* W5 = (const float*)d_in[28];
    const float* b5 = (const float*)d_in[29];
    const int* ei    = (const int*)d_in[30];
    const int* batch = (const int*)d_in[31];
    float* out = (float*)d_out;

    const size_t NH = (size_t)N_NODES * H;
    const size_t AH = (size_t)MP * 128;       // bf16 elements per A buffer
    const size_t WH = (size_t)3 * 512 * 128;  // bf16 elements per W buffer
    float* Kb   = (float*)d_ws;
    float* Qb   = Kb + NH;
    float* Vb   = Qb + NH;
    float* hbuf = Vb + NH;
    short* Ahb  = (short*)(hbuf + NH);
    short* Alb  = Ahb + AH;
    short* Wth  = Alb + AH;
    short* Wtl  = Wth + WH;
    float* hg   = (float*)(Wtl + WH);                 // G*H
    int*   off  = (int*)(hg + (size_t)N_GRAPHS * H);  // N+1
    int*   cnt  = off + (N_NODES + 1);
    int*   csr  = cnt + N_NODES;
    int*   gst  = csr + N_EDGES;
    const size_t need = (4 * NH + (size_t)N_GRAPHS * H) * sizeof(float)
                      + (2 * AH + 2 * WH) * sizeof(short)
                      + (size_t)(2 * N_NODES + 1 + N_EDGES + N_GRAPHS + 1) * sizeof(int);
    if (ws_size < need) return;

    const int eblk = (N_EDGES + 255) / 256;
    const int ablk = (N_NODES + 3) / 4;
    const int nblk = (N_NODES + 255) / 256;
    const int cablk = (MP * 16) / 256;        // conv_A blocks
    const dim3 ggrid(MP / 128, 4);

    // ---- CSR + graph segments + weight conversion (reused across layers)
    hipMemsetAsync(cnt, 0, N_NODES * sizeof(int), stream);
    hist_kernel<<<eblk, 256, 0, stream>>>(ei, cnt, N_EDGES);
    scan_kernel<<<1, 1024, 0, stream>>>(cnt, off, N_NODES);
    scatter_kernel<<<eblk, 256, 0, stream>>>(ei, cnt, csr, N_EDGES);
    gstart_kernel<<<nblk, 256, 0, stream>>>(batch, gst, N_NODES);
    conv_W<<<256, 256, 0, stream>>>(Wk[0], Wq[0], Wv[0], Wsk[0], DIN, Wth,              Wtl);
    conv_W<<<256, 256, 0, stream>>>(Wk[1], Wq[1], Wv[1], Wsk[1], H,   Wth + 512 * 128, Wtl + 512 * 128);
    conv_W<<<256, 256, 0, stream>>>(Wk[2], Wq[2], Wv[2], Wsk[2], H,   Wth + 1024 * 128, Wtl + 1024 * 128);

    // ---- Layer 1
    conv_A<<<cablk, 256, 0, stream>>>(x, N_NODES, DIN, 0, Ahb, Alb);
    gemm_mfma<<<ggrid, 256, 0, stream>>>(Ahb, Alb, Wth, Wtl,
        bk[0], bq[0], bv[0], bs[0], Kb, Qb, Vb, hbuf, N_NODES);
    agg_csr<<<ablk, 256, 0, stream>>>(Kb, Qb, Vb, off, csr, hbuf, N_NODES);

    // ---- Layer 2
    conv_A<<<cablk, 256, 0, stream>>>(hbuf, N_NODES, H, 1, Ahb, Alb);
    gemm_mfma<<<ggrid, 256, 0, stream>>>(Ahb, Alb, Wth + 512 * 128, Wtl + 512 * 128,
        bk[1], bq[1], bv[1], bs[1], Kb, Qb, Vb, hbuf, N_NODES);
    agg_csr<<<ablk, 256, 0, stream>>>(Kb, Qb, Vb, off, csr, hbuf, N_NODES);

    // ---- Layer 3
    conv_A<<<cablk, 256, 0, stream>>>(hbuf, N_NODES, H, 1, Ahb, Alb);
    gemm_mfma<<<ggrid, 256, 0, stream>>>(Ahb, Alb, Wth + 1024 * 128, Wtl + 1024 * 128,
        bk[2], bq[2], bv[2], bs[2], Kb, Qb, Vb, hbuf, N_NODES);
    agg_csr<<<ablk, 256, 0, stream>>>(Kb, Qb, Vb, off, csr, hbuf, N_NODES);

    // ---- Pool + MLP
    pool_seg<<<N_GRAPHS, 128, 0, stream>>>(hbuf, gst, hg);
    mlp_kernel<<<N_GRAPHS, 64, 0, stream>>>(hg, W4, b4, W5, b5, out);
}

// Round 4
// 744.695 us; speedup vs baseline: 6.5242x; 1.1505x over previous
//
#include <hip/hip_runtime.h>

#define N_NODES 50000
#define N_EDGES 800000
#define N_GRAPHS 256
#define DIN 126
#define H 128
#define MP 50048           // N_NODES padded to 128
#define NB_SCAN 196        // ceil(N_NODES/256)

typedef __attribute__((ext_vector_type(8))) short short8v;
typedef __attribute__((ext_vector_type(4))) float f32x4;

// ---------------------------------------------------------------------------
// fp32 -> bf16 hi/lo split helpers (RNE)
// ---------------------------------------------------------------------------
__device__ __forceinline__ unsigned short f2bf(float f) {
    const unsigned u = __float_as_uint(f);
    return (unsigned short)((u + 0x7FFFu + ((u >> 16) & 1u)) >> 16);
}
__device__ __forceinline__ float bf2f(unsigned short s) {
    return __uint_as_float(((unsigned)s) << 16);
}

// ---------------------------------------------------------------------------
// A conversion: X fp32 [M,Kd] (+optional relu) -> Ah,Al bf16 [MP][128]
// ---------------------------------------------------------------------------
__global__ __launch_bounds__(256) void conv_A(const float* __restrict__ X, int M, int Kd,
                                              int relu, short* __restrict__ Ah,
                                              short* __restrict__ Al)
{
    const int t = blockIdx.x * 256 + threadIdx.x;
    const int row = t >> 4;
    if (row >= MP) return;
    const int k0 = (t & 15) * 8;
    short8v hv, lv;
    #pragma unroll
    for (int j = 0; j < 8; ++j) {
        const int k = k0 + j;
        float v = 0.f;
        if (row < M && k < Kd) v = X[(size_t)row * Kd + k];
        if (relu) v = fmaxf(v, 0.f);
        const unsigned short hb = f2bf(v);
        const float lo = v - bf2f(hb);
        hv[j] = (short)hb;
        lv[j] = (short)f2bf(lo);
    }
    const size_t o = (size_t)row * 128 + k0;
    *(short8v*)&Ah[o] = hv;
    *(short8v*)&Al[o] = lv;
}

// ---------------------------------------------------------------------------
// W conversion (one layer): four [Kd,128] fp32 -> transposed Wth/Wtl bf16
// ---------------------------------------------------------------------------
__global__ __launch_bounds__(256) void conv_W(
    const float* __restrict__ W0, const float* __restrict__ W1,
    const float* __restrict__ W2, const float* __restrict__ W3,
    int Kd, short* __restrict__ Wth, short* __restrict__ Wtl)
{
    const int t = blockIdx.x * 256 + threadIdx.x;
    if (t >= 512 * 128) return;
    const int n = t >> 7, k = t & 127;
    const int mtx = n >> 7, cc = n & 127;
    const float* W = mtx == 0 ? W0 : mtx == 1 ? W1 : mtx == 2 ? W2 : W3;
    const float v = (k < Kd) ? W[(size_t)k * 128 + cc] : 0.f;
    const unsigned short hb = f2bf(v);
    Wth[t] = (short)hb;
    Wtl[t] = (short)f2bf(v - bf2f(hb));
}

// ---------------------------------------------------------------------------
// MFMA GEMM (hi/lo split) — unchanged from R3.
// ---------------------------------------------------------------------------
__global__ __launch_bounds__(256) void gemm_mfma(
    const short* __restrict__ Ah, const short* __restrict__ Al,
    const short* __restrict__ Wth, const short* __restrict__ Wtl,
    const float* __restrict__ bias0, const float* __restrict__ bias1,
    const float* __restrict__ bias2, const float* __restrict__ bias3,
    float* __restrict__ O0, float* __restrict__ O1,
    float* __restrict__ O2, float* __restrict__ O3, int M)
{
    __shared__ short lds[4][8192];
    const int t = threadIdx.x;
    const int l = t & 63, w = t >> 6;
    const int wr = w >> 1, wc = w & 1;
    const int mtx = blockIdx.y;
    const int row0 = blockIdx.x * 128;
    const int ncol0 = mtx * 128;

    f32x4 acc[4][4] = {};

    for (int c = 0; c < 2; ++c) {
        __syncthreads();
        #pragma unroll
        for (int i = 0; i < 4; ++i) {
            const int li = i * 256 + t;
            const int r = li >> 3, k16 = li & 7;
            const int lo = r * 64 + ((k16 ^ (r & 7)) * 8);
            const size_t ga = (size_t)(row0 + r) * 128 + c * 64 + k16 * 8;
            const size_t gw = (size_t)(ncol0 + r) * 128 + c * 64 + k16 * 8;
            *(short8v*)&lds[0][lo] = *(const short8v*)&Ah[ga];
            *(short8v*)&lds[1][lo] = *(const short8v*)&Al[ga];
            *(short8v*)&lds[2][lo] = *(const short8v*)&Wth[gw];
            *(short8v*)&lds[3][lo] = *(const short8v*)&Wtl[gw];
        }
        __syncthreads();
        #pragma unroll
        for (int s = 0; s < 2; ++s) {
            short8v ah[4], al[4], wh[4], wl[4];
            const int kg = s * 4 + (l >> 4);
            #pragma unroll
            for (int m = 0; m < 4; ++m) {
                const int ar = wr * 64 + m * 16 + (l & 15);
                const int ao = ar * 64 + ((kg ^ (ar & 7)) * 8);
                ah[m] = *(const short8v*)&lds[0][ao];
                al[m] = *(const short8v*)&lds[1][ao];
                const int br = wc * 64 + m * 16 + (l & 15);
                const int bo = br * 64 + ((kg ^ (br & 7)) * 8);
                wh[m] = *(const short8v*)&lds[2][bo];
                wl[m] = *(const short8v*)&lds[3][bo];
            }
            #pragma unroll
            for (int m = 0; m < 4; ++m)
                #pragma unroll
                for (int n = 0; n < 4; ++n) {
                    acc[m][n] = __builtin_amdgcn_mfma_f32_16x16x32_bf16(ah[m], wh[n], acc[m][n], 0, 0, 0);
                    acc[m][n] = __builtin_amdgcn_mfma_f32_16x16x32_bf16(ah[m], wl[n], acc[m][n], 0, 0, 0);
                    acc[m][n] = __builtin_amdgcn_mfma_f32_16x16x32_bf16(al[m], wh[n], acc[m][n], 0, 0, 0);
                }
        }
    }

    const float* bias = mtx == 0 ? bias0 : mtx == 1 ? bias1 : mtx == 2 ? bias2 : bias3;
    float*       O    = mtx == 0 ? O0    : mtx == 1 ? O1    : mtx == 2 ? O2    : O3;
    #pragma unroll
    for (int n = 0; n < 4; ++n) {
        const int col = wc * 64 + n * 16 + (l & 15);
        const float bv = bias[col];
        #pragma unroll
        for (int m = 0; m < 4; ++m) {
            const int rb = row0 + wr * 64 + m * 16 + ((l >> 4) * 4);
            #pragma unroll
            for (int j = 0; j < 4; ++j) {
                const int r = rb + j;
                if (r < M) O[(size_t)r * 128 + col] = acc[m][n][j] + bv;
            }
        }
    }
}

// ---------------------------------------------------------------------------
// CSR build: histogram, hierarchical scan (3 parallel kernels), scatter.
// ---------------------------------------------------------------------------
__global__ __launch_bounds__(256) void hist_kernel(const int* __restrict__ ei,
                                                   int* __restrict__ cnt, int E)
{
    const int e = blockIdx.x * 256 + threadIdx.x;
    if (e < E) atomicAdd(&cnt[ei[E + e]], 1);
}

// per-block sum of cnt
__global__ __launch_bounds__(256) void scan_p1(const int* __restrict__ cnt,
                                               int* __restrict__ bsum, int Nn)
{
    __shared__ int red[256];
    const int t = threadIdx.x;
    const int i = blockIdx.x * 256 + t;
    red[t] = (i < Nn) ? cnt[i] : 0;
    __syncthreads();
    for (int d = 128; d > 0; d >>= 1) {
        if (t < d) red[t] += red[t + d];
        __syncthreads();
    }
    if (t == 0) bsum[blockIdx.x] = red[0];
}

// single block: exclusive scan of NB_SCAN block sums; also writes off[Nn]=E.
__global__ __launch_bounds__(256) void scan_p2(const int* __restrict__ bsum,
                                               int* __restrict__ bsoff,
                                               int* __restrict__ off, int Nn)
{
    __shared__ int sc[256];
    const int t = threadIdx.x;
    const int v = (t < NB_SCAN) ? bsum[t] : 0;
    sc[t] = v;
    __syncthreads();
    #pragma unroll
    for (int d = 1; d < 256; d <<= 1) {
        const int a = (t >= d) ? sc[t - d] : 0;
        __syncthreads();
        sc[t] += a;
        __syncthreads();
    }
    if (t < NB_SCAN) bsoff[t] = sc[t] - v;
    if (t == NB_SCAN - 1) off[Nn] = sc[t];
}

// per-block local exclusive scan + block offset -> off[] and cursor cnt[]
__global__ __launch_bounds__(256) void scan_p3(int* __restrict__ cnt,
                                               const int* __restrict__ bsoff,
                                               int* __restrict__ off, int Nn)
{
    __shared__ int sc[256];
    const int t = threadIdx.x;
    const int i = blockIdx.x * 256 + t;
    const int v = (i < Nn) ? cnt[i] : 0;
    sc[t] = v;
    __syncthreads();
    #pragma unroll
    for (int d = 1; d < 256; d <<= 1) {
        const int a = (t >= d) ? sc[t - d] : 0;
        __syncthreads();
        sc[t] += a;
        __syncthreads();
    }
    if (i < Nn) {
        const int o = bsoff[blockIdx.x] + sc[t] - v;
        off[i] = o;
        cnt[i] = o;   // scatter cursor
    }
}

__global__ __launch_bounds__(256) void scatter_kernel(const int* __restrict__ ei,
                                                      int* __restrict__ cur,
                                                      int* __restrict__ csr_src, int E)
{
    const int e = blockIdx.x * 256 + threadIdx.x;
    if (e >= E) return;
    const int s = ei[e];
    const int d = ei[E + e];
    const int pos = atomicAdd(&cur[d], 1);
    csr_src[pos] = s;
}

// ---------------------------------------------------------------------------
// CSR aggregation v2: one wave per dst node, two 32-lane halves process
// 2 edges/iteration (float4 per lane), __shfl_xor(32) combine at the end.
// ---------------------------------------------------------------------------
__global__ __launch_bounds__(256) void agg_csr(
    const float* __restrict__ Kb, const float* __restrict__ Qb,
    const float* __restrict__ Vb, const int* __restrict__ off,
    const int* __restrict__ csr_src, float* __restrict__ hOut, int Nn)
{
    const int node = blockIdx.x * 4 + (threadIdx.x >> 6);
    if (node >= Nn) return;
    const int lane = threadIdx.x & 63;
    const int half = lane >> 5;          // 0: even edges, 1: odd edges
    const int q = (lane & 31) * 4;       // dim offset (both halves cover 0..127)

    const float4 kv = *(const float4*)(Kb + (size_t)node * H + q);
    float4 acc = make_float4(0.f, 0.f, 0.f, 0.f);

    const int begin = off[node], end = off[node + 1];
    for (int j0 = begin; j0 < end; j0 += 64) {
        const int nrem = end - j0;
        const int nk = nrem < 64 ? nrem : 64;
        const int sv = (lane < nk) ? csr_src[j0 + lane] : 0;
        #pragma unroll 4
        for (int k2 = 0; k2 < nk; k2 += 2) {
            const int myk = k2 + half;
            const int s = __shfl(sv, myk < nk ? myk : 0);
            if (myk < nk) {
                const float4 qv = *(const float4*)(Qb + (size_t)s * H + q);
                const float4 vv = *(const float4*)(Vb + (size_t)s * H + q);
                acc.x += vv.x / (1.f + __expf(-(kv.x + qv.x)));
                acc.y += vv.y / (1.f + __expf(-(kv.y + qv.y)));
                acc.z += vv.z / (1.f + __expf(-(kv.z + qv.z)));
                acc.w += vv.w / (1.f + __expf(-(kv.w + qv.w)));
            }
        }
    }
    // combine the two halves, lanes 0-31 store
    float4 oth;
    oth.x = __shfl_xor(acc.x, 32);
    oth.y = __shfl_xor(acc.y, 32);
    oth.z = __shfl_xor(acc.z, 32);
    oth.w = __shfl_xor(acc.w, 32);
    if (half == 0) {
        float* o = hOut + (size_t)node * H + q;
        float4 ex = *(const float4*)o;
        ex.x += acc.x + oth.x;
        ex.y += acc.y + oth.y;
        ex.z += acc.z + oth.z;
        ex.w += acc.w + oth.w;
        *(float4*)o = ex;
    }
}

// ---------------------------------------------------------------------------
// Pool + MLP (unchanged)
// ---------------------------------------------------------------------------
__global__ __launch_bounds__(256) void gstart_kernel(const int* __restrict__ batch,
                                                     int* __restrict__ gstart, int Nn)
{
    const int n = blockIdx.x * 256 + threadIdx.x;
    if (n >= Nn) return;
    const int b = batch[n];
    const int bp = (n == 0) ? -1 : batch[n - 1];
    for (int g = bp + 1; g <= b; ++g) gstart[g] = n;
    if (n == Nn - 1)
        for (int g = b + 1; g <= N_GRAPHS; ++g) gstart[g] = Nn;
}

__global__ __launch_bounds__(128) void pool_seg(const float* __restrict__ h,
                                                const int* __restrict__ gstart,
                                                float* __restrict__ hg)
{
    const int g = blockIdx.x;
    const int t = threadIdx.x;
    const int b0 = gstart[g], b1 = gstart[g + 1];
    float acc = 0.f;
    for (int n = b0; n < b1; ++n) acc += h[(size_t)n * H + t];
    hg[(size_t)g * H + t] = acc;
}

__global__ __launch_bounds__(64) void mlp_kernel(
    const float* __restrict__ hg,
    const float* __restrict__ W4, const float* __restrict__ b4,
    const float* __restrict__ W5, const float* __restrict__ b5,
    float* __restrict__ out)
{
    const int g = blockIdx.x;
    const int c = threadIdx.x;
    __shared__ float hrow[H];
    for (int k = c; k < H; k += 64) hrow[k] = hg[(size_t)g * H + k];
    __syncthreads();
    float s = b4[c];
    #pragma unroll 8
    for (int k = 0; k < H; ++k) s += hrow[k] * W4[(size_t)k * 64 + c];
    s = fmaxf(s, 0.f) * W5[c];
    #pragma unroll
    for (int off = 32; off > 0; off >>= 1) s += __shfl_down(s, off);
    if (c == 0) out[g] = 1.f / (1.f + __expf(-(s + b5[0])));
}

// ---------------------------------------------------------------------------
extern "C" void kernel_launch(void* const* d_in, const int* in_sizes, int n_in,
                              void* d_out, int out_size, void* d_ws, size_t ws_size,
                              hipStream_t stream)
{
    const float* x = (const float*)d_in[0];
    const float *Wk[3], *bk[3], *Wq[3], *bq[3], *Wv[3], *bv[3], *Wsk[3], *bs[3];
    for (int l = 0; l < 3; ++l) {
        const int base = 2 + l * 8;
        Wk[l]  = (const float*)d_in[base + 0]; bk[l] = (const float*)d_in[base + 1];
        Wq[l]  = (const float*)d_in[base + 2]; bq[l] = (const float*)d_in[base + 3];
        Wv[l]  = (const float*)d_in[base + 4]; bv[l] = (const float*)d_in[base + 5];
        Wsk[l] = (const float*)d_in[base + 6]; bs[l] = (const float*)d_in[base + 7];
    }
    const float* W4 = (const float*)d_in[26];
    const float* b4 = (const float*)d_in[27];
    const float* W5 = (const float*)d_in[28];
    const float* b5 = (const float*)d_in[29];
    const int* ei    = (const int*)d_in[30];
    const int* batch = (const int*)d_in[31];
    float* out = (float*)d_out;

    const size_t NH = (size_t)N_NODES * H;
    const size_t AH = (size_t)MP * 128;
    const size_t WH = (size_t)3 * 512 * 128;
    float* Kb   = (float*)d_ws;
    float* Qb   = Kb + NH;
    float* Vb   = Qb + NH;
    float* hbuf = Vb + NH;
    short* Ahb  = (short*)(hbuf + NH);
    short* Alb  = Ahb + AH;
    short* Wth  = Alb + AH;
    short* Wtl  = Wth + WH;
    float* hg   = (float*)(Wtl + WH);
    int*   off  = (int*)(hg + (size_t)N_GRAPHS * H);  // N+1
    int*   cnt  = off + (N_NODES + 1);
    int*   csr  = cnt + N_NODES;
    int*   gst  = csr + N_EDGES;                      // G+1
    int*   bsum = gst + (N_GRAPHS + 1);               // 256
    int*   bsoff= bsum + 256;                         // 256
    const size_t need = (4 * NH + (size_t)N_GRAPHS * H) * sizeof(float)
                      + (2 * AH + 2 * WH) * sizeof(short)
                      + (size_t)(2 * N_NODES + 1 + N_EDGES + N_GRAPHS + 1 + 512) * sizeof(int);
    if (ws_size < need) return;

    const int eblk = (N_EDGES + 255) / 256;
    const int ablk = (N_NODES + 3) / 4;
    const int nblk = (N_NODES + 255) / 256;
    const int cablk = (MP * 16) / 256;
    const dim3 ggrid(MP / 128, 4);

    // ---- CSR + graph segments + weight conversion (reused across layers)
    hipMemsetAsync(cnt, 0, N_NODES * sizeof(int), stream);
    hist_kernel<<<eblk, 256, 0, stream>>>(ei, cnt, N_EDGES);
    scan_p1<<<NB_SCAN, 256, 0, stream>>>(cnt, bsum, N_NODES);
    scan_p2<<<1, 256, 0, stream>>>(bsum, bsoff, off, N_NODES);
    scan_p3<<<NB_SCAN, 256, 0, stream>>>(cnt, bsoff, off, N_NODES);
    scatter_kernel<<<eblk, 256, 0, stream>>>(ei, cnt, csr, N_EDGES);
    gstart_kernel<<<nblk, 256, 0, stream>>>(batch, gst, N_NODES);
    conv_W<<<256, 256, 0, stream>>>(Wk[0], Wq[0], Wv[0], Wsk[0], DIN, Wth,               Wtl);
    conv_W<<<256, 256, 0, stream>>>(Wk[1], Wq[1], Wv[1], Wsk[1], H,   Wth + 512 * 128,  Wtl + 512 * 128);
    conv_W<<<256, 256, 0, stream>>>(Wk[2], Wq[2], Wv[2], Wsk[2], H,   Wth + 1024 * 128, Wtl + 1024 * 128);

    // ---- Layer 1
    conv_A<<<cablk, 256, 0, stream>>>(x, N_NODES, DIN, 0, Ahb, Alb);
    gemm_mfma<<<ggrid, 256, 0, stream>>>(Ahb, Alb, Wth, Wtl,
        bk[0], bq[0], bv[0], bs[0], Kb, Qb, Vb, hbuf, N_NODES);
    agg_csr<<<ablk, 256, 0, stream>>>(Kb, Qb, Vb, off, csr, hbuf, N_NODES);

    // ---- Layer 2
    conv_A<<<cablk, 256, 0, stream>>>(hbuf, N_NODES, H, 1, Ahb, Alb);
    gemm_mfma<<<ggrid, 256, 0, stream>>>(Ahb, Alb, Wth + 512 * 128, Wtl + 512 * 128,
        bk[1], bq[1], bv[1], bs[1], Kb, Qb, Vb, hbuf, N_NODES);
    agg_csr<<<ablk, 256, 0, stream>>>(Kb, Qb, Vb, off, csr, hbuf, N_NODES);

    // ---- Layer 3
    conv_A<<<cablk, 256, 0, stream>>>(hbuf, N_NODES, H, 1, Ahb, Alb);
    gemm_mfma<<<ggrid, 256, 0, stream>>>(Ahb, Alb, Wth + 1024 * 128, Wtl + 1024 * 128,
        bk[2], bq[2], bv[2], bs[2], Kb, Qb, Vb, hbuf, N_NODES);
    agg_csr<<<ablk, 256, 0, stream>>>(Kb, Qb, Vb, off, csr, hbuf, N_NODES);

    // ---- Pool + MLP
    pool_seg<<<N_GRAPHS, 128, 0, stream>>>(hbuf, gst, hg);
    mlp_kernel<<<N_GRAPHS, 64, 0, stream>>>(hg, W4, b4, W5, b5, out);
}

// Round 5
// 574.090 us; speedup vs baseline: 8.4630x; 1.2972x over previous
//
#include <hip/hip_runtime.h>

#define N_NODES 50000
#define N_EDGES 800000
#define N_GRAPHS 256
#define DIN 126
#define H 128
#define MP 50048           // N_NODES padded to 128
#define NB_SCAN 196        // ceil(N_NODES/256)

typedef __attribute__((ext_vector_type(8))) short short8v;
typedef __attribute__((ext_vector_type(8))) _Float16 half8v;
typedef __attribute__((ext_vector_type(4))) float f32x4;

// ---------------------------------------------------------------------------
// fp32 -> bf16 hi/lo split helpers (RNE)
// ---------------------------------------------------------------------------
__device__ __forceinline__ unsigned short f2bf(float f) {
    const unsigned u = __float_as_uint(f);
    return (unsigned short)((u + 0x7FFFu + ((u >> 16) & 1u)) >> 16);
}
__device__ __forceinline__ float bf2f(unsigned short s) {
    return __uint_as_float(((unsigned)s) << 16);
}

// ---------------------------------------------------------------------------
// A conversion: X fp32 [M,Kd] (+optional relu) -> Ah,Al bf16 [MP][128]
// ---------------------------------------------------------------------------
__global__ __launch_bounds__(256) void conv_A(const float* __restrict__ X, int M, int Kd,
                                              int relu, short* __restrict__ Ah,
                                              short* __restrict__ Al)
{
    const int t = blockIdx.x * 256 + threadIdx.x;
    const int row = t >> 4;
    if (row >= MP) return;
    const int k0 = (t & 15) * 8;
    short8v hv, lv;
    #pragma unroll
    for (int j = 0; j < 8; ++j) {
        const int k = k0 + j;
        float v = 0.f;
        if (row < M && k < Kd) v = X[(size_t)row * Kd + k];
        if (relu) v = fmaxf(v, 0.f);
        const unsigned short hb = f2bf(v);
        const float lo = v - bf2f(hb);
        hv[j] = (short)hb;
        lv[j] = (short)f2bf(lo);
    }
    const size_t o = (size_t)row * 128 + k0;
    *(short8v*)&Ah[o] = hv;
    *(short8v*)&Al[o] = lv;
}

// ---------------------------------------------------------------------------
// W conversion (one layer): four [Kd,128] fp32 -> transposed Wth/Wtl bf16
// ---------------------------------------------------------------------------
__global__ __launch_bounds__(256) void conv_W(
    const float* __restrict__ W0, const float* __restrict__ W1,
    const float* __restrict__ W2, const float* __restrict__ W3,
    int Kd, short* __restrict__ Wth, short* __restrict__ Wtl)
{
    const int t = blockIdx.x * 256 + threadIdx.x;
    if (t >= 512 * 128) return;
    const int n = t >> 7, k = t & 127;
    const int mtx = n >> 7, cc = n & 127;
    const float* W = mtx == 0 ? W0 : mtx == 1 ? W1 : mtx == 2 ? W2 : W3;
    const float v = (k < Kd) ? W[(size_t)k * 128 + cc] : 0.f;
    const unsigned short hb = f2bf(v);
    Wth[t] = (short)hb;
    Wtl[t] = (short)f2bf(v - bf2f(hb));
}

// ---------------------------------------------------------------------------
// MFMA GEMM (hi/lo split).  Outputs: K (fp32), Q (fp16), V (fp16), skip (fp32).
// ---------------------------------------------------------------------------
__global__ __launch_bounds__(256) void gemm_mfma(
    const short* __restrict__ Ah, const short* __restrict__ Al,
    const short* __restrict__ Wth, const short* __restrict__ Wtl,
    const float* __restrict__ bias0, const float* __restrict__ bias1,
    const float* __restrict__ bias2, const float* __restrict__ bias3,
    float* __restrict__ OK, _Float16* __restrict__ OQ,
    _Float16* __restrict__ OV, float* __restrict__ OS, int M)
{
    __shared__ short lds[4][8192];
    const int t = threadIdx.x;
    const int l = t & 63, w = t >> 6;
    const int wr = w >> 1, wc = w & 1;
    const int mtx = blockIdx.y;
    const int row0 = blockIdx.x * 128;
    const int ncol0 = mtx * 128;

    f32x4 acc[4][4] = {};

    for (int c = 0; c < 2; ++c) {
        __syncthreads();
        #pragma unroll
        for (int i = 0; i < 4; ++i) {
            const int li = i * 256 + t;
            const int r = li >> 3, k16 = li & 7;
            const int lo = r * 64 + ((k16 ^ (r & 7)) * 8);
            const size_t ga = (size_t)(row0 + r) * 128 + c * 64 + k16 * 8;
            const size_t gw = (size_t)(ncol0 + r) * 128 + c * 64 + k16 * 8;
            *(short8v*)&lds[0][lo] = *(const short8v*)&Ah[ga];
            *(short8v*)&lds[1][lo] = *(const short8v*)&Al[ga];
            *(short8v*)&lds[2][lo] = *(const short8v*)&Wth[gw];
            *(short8v*)&lds[3][lo] = *(const short8v*)&Wtl[gw];
        }
        __syncthreads();
        #pragma unroll
        for (int s = 0; s < 2; ++s) {
            short8v ah[4], al[4], wh[4], wl[4];
            const int kg = s * 4 + (l >> 4);
            #pragma unroll
            for (int m = 0; m < 4; ++m) {
                const int ar = wr * 64 + m * 16 + (l & 15);
                const int ao = ar * 64 + ((kg ^ (ar & 7)) * 8);
                ah[m] = *(const short8v*)&lds[0][ao];
                al[m] = *(const short8v*)&lds[1][ao];
                const int br = wc * 64 + m * 16 + (l & 15);
                const int bo = br * 64 + ((kg ^ (br & 7)) * 8);
                wh[m] = *(const short8v*)&lds[2][bo];
                wl[m] = *(const short8v*)&lds[3][bo];
            }
            #pragma unroll
            for (int m = 0; m < 4; ++m)
                #pragma unroll
                for (int n = 0; n < 4; ++n) {
                    acc[m][n] = __builtin_amdgcn_mfma_f32_16x16x32_bf16(ah[m], wh[n], acc[m][n], 0, 0, 0);
                    acc[m][n] = __builtin_amdgcn_mfma_f32_16x16x32_bf16(ah[m], wl[n], acc[m][n], 0, 0, 0);
                    acc[m][n] = __builtin_amdgcn_mfma_f32_16x16x32_bf16(al[m], wh[n], acc[m][n], 0, 0, 0);
                }
        }
    }

    const float* bias = mtx == 0 ? bias0 : mtx == 1 ? bias1 : mtx == 2 ? bias2 : bias3;
    if (mtx == 0 || mtx == 3) {
        float* O = (mtx == 0) ? OK : OS;
        #pragma unroll
        for (int n = 0; n < 4; ++n) {
            const int col = wc * 64 + n * 16 + (l & 15);
            const float bv = bias[col];
            #pragma unroll
            for (int m = 0; m < 4; ++m) {
                const int rb = row0 + wr * 64 + m * 16 + ((l >> 4) * 4);
                #pragma unroll
                for (int j = 0; j < 4; ++j) {
                    const int r = rb + j;
                    if (r < M) O[(size_t)r * 128 + col] = acc[m][n][j] + bv;
                }
            }
        }
    } else {
        _Float16* O = (mtx == 1) ? OQ : OV;
        #pragma unroll
        for (int n = 0; n < 4; ++n) {
            const int col = wc * 64 + n * 16 + (l & 15);
            const float bv = bias[col];
            #pragma unroll
            for (int m = 0; m < 4; ++m) {
                const int rb = row0 + wr * 64 + m * 16 + ((l >> 4) * 4);
                #pragma unroll
                for (int j = 0; j < 4; ++j) {
                    const int r = rb + j;
                    if (r < M) O[(size_t)r * 128 + col] = (_Float16)(acc[m][n][j] + bv);
                }
            }
        }
    }
}

// ---------------------------------------------------------------------------
// CSR build: histogram, hierarchical scan, scatter.  (unchanged from R4)
// ---------------------------------------------------------------------------
__global__ __launch_bounds__(256) void hist_kernel(const int* __restrict__ ei,
                                                   int* __restrict__ cnt, int E)
{
    const int e = blockIdx.x * 256 + threadIdx.x;
    if (e < E) atomicAdd(&cnt[ei[E + e]], 1);
}

__global__ __launch_bounds__(256) void scan_p1(const int* __restrict__ cnt,
                                               int* __restrict__ bsum, int Nn)
{
    __shared__ int red[256];
    const int t = threadIdx.x;
    const int i = blockIdx.x * 256 + t;
    red[t] = (i < Nn) ? cnt[i] : 0;
    __syncthreads();
    for (int d = 128; d > 0; d >>= 1) {
        if (t < d) red[t] += red[t + d];
        __syncthreads();
    }
    if (t == 0) bsum[blockIdx.x] = red[0];
}

__global__ __launch_bounds__(256) void scan_p2(const int* __restrict__ bsum,
                                               int* __restrict__ bsoff,
                                               int* __restrict__ off, int Nn)
{
    __shared__ int sc[256];
    const int t = threadIdx.x;
    const int v = (t < NB_SCAN) ? bsum[t] : 0;
    sc[t] = v;
    __syncthreads();
    #pragma unroll
    for (int d = 1; d < 256; d <<= 1) {
        const int a = (t >= d) ? sc[t - d] : 0;
        __syncthreads();
        sc[t] += a;
        __syncthreads();
    }
    if (t < NB_SCAN) bsoff[t] = sc[t] - v;
    if (t == NB_SCAN - 1) off[Nn] = sc[t];
}

__global__ __launch_bounds__(256) void scan_p3(int* __restrict__ cnt,
                                               const int* __restrict__ bsoff,
                                               int* __restrict__ off, int Nn)
{
    __shared__ int sc[256];
    const int t = threadIdx.x;
    const int i = blockIdx.x * 256 + t;
    const int v = (i < Nn) ? cnt[i] : 0;
    sc[t] = v;
    __syncthreads();
    #pragma unroll
    for (int d = 1; d < 256; d <<= 1) {
        const int a = (t >= d) ? sc[t - d] : 0;
        __syncthreads();
        sc[t] += a;
        __syncthreads();
    }
    if (i < Nn) {
        const int o = bsoff[blockIdx.x] + sc[t] - v;
        off[i] = o;
        cnt[i] = o;
    }
}

__global__ __launch_bounds__(256) void scatter_kernel(const int* __restrict__ ei,
                                                      int* __restrict__ cur,
                                                      int* __restrict__ csr_src, int E)
{
    const int e = blockIdx.x * 256 + threadIdx.x;
    if (e >= E) return;
    const int s = ei[e];
    const int d = ei[E + e];
    const int pos = atomicAdd(&cur[d], 1);
    csr_src[pos] = s;
}

// ---------------------------------------------------------------------------
// CSR aggregation v3: fp16 Q/V gathers, 16 lanes per edge (4 edges in flight
// per wave), fp32 K and accumulation, cross-group shfl reduce, fp32 RMW store.
// ---------------------------------------------------------------------------
__global__ __launch_bounds__(256) void agg_csr(
    const float* __restrict__ Kb, const _Float16* __restrict__ Q16,
    const _Float16* __restrict__ V16, const int* __restrict__ off,
    const int* __restrict__ csr_src, float* __restrict__ hOut, int Nn)
{
    const int node = blockIdx.x * 4 + (threadIdx.x >> 6);
    if (node >= Nn) return;
    const int lane = threadIdx.x & 63;
    const int grp = lane >> 4;           // 0..3: which edge of the quad
    const int sub = lane & 15;           // 16 lanes x 8 dims = 128
    const int q = sub * 8;

    const float4 kA = *(const float4*)(Kb + (size_t)node * H + q);
    const float4 kB = *(const float4*)(Kb + (size_t)node * H + q + 4);
    float acc[8] = {};

    const int begin = off[node], end = off[node + 1];
    for (int j0 = begin; j0 < end; j0 += 64) {
        const int nrem = end - j0;
        const int nk = nrem < 64 ? nrem : 64;
        const int sv = (lane < nk) ? csr_src[j0 + lane] : 0;
        #pragma unroll 2
        for (int k = 0; k < nk; k += 4) {
            const int myk = k + grp;
            const int s = __shfl(sv, myk < nk ? myk : 0);
            if (myk < nk) {
                const half8v qv = *(const half8v*)(Q16 + (size_t)s * H + q);
                const half8v vv = *(const half8v*)(V16 + (size_t)s * H + q);
                acc[0] += (float)vv[0] / (1.f + __expf(-(kA.x + (float)qv[0])));
                acc[1] += (float)vv[1] / (1.f + __expf(-(kA.y + (float)qv[1])));
                acc[2] += (float)vv[2] / (1.f + __expf(-(kA.z + (float)qv[2])));
                acc[3] += (float)vv[3] / (1.f + __expf(-(kA.w + (float)qv[3])));
                acc[4] += (float)vv[4] / (1.f + __expf(-(kB.x + (float)qv[4])));
                acc[5] += (float)vv[5] / (1.f + __expf(-(kB.y + (float)qv[5])));
                acc[6] += (float)vv[6] / (1.f + __expf(-(kB.z + (float)qv[6])));
                acc[7] += (float)vv[7] / (1.f + __expf(-(kB.w + (float)qv[7])));
            }
        }
    }
    // sum the 4 edge-groups (butterfly over lane bits 4,5)
    #pragma unroll
    for (int i = 0; i < 8; ++i) {
        acc[i] += __shfl_xor(acc[i], 16);
        acc[i] += __shfl_xor(acc[i], 32);
    }
    if (grp == 0) {
        float* o = hOut + (size_t)node * H + q;
        float4 eA = *(const float4*)o;
        float4 eB = *(const float4*)(o + 4);
        eA.x += acc[0]; eA.y += acc[1]; eA.z += acc[2]; eA.w += acc[3];
        eB.x += acc[4]; eB.y += acc[5]; eB.z += acc[6]; eB.w += acc[7];
        *(float4*)o = eA;
        *(float4*)(o + 4) = eB;
    }
}

// ---------------------------------------------------------------------------
// Pool: grid (G, 4); each block sums a quarter of the graph's segment,
// atomicAdd partials into hg (hg zeroed by the fused memset).
// ---------------------------------------------------------------------------
__global__ __launch_bounds__(256) void gstart_kernel(const int* __restrict__ batch,
                                                     int* __restrict__ gstart, int Nn)
{
    const int n = blockIdx.x * 256 + threadIdx.x;
    if (n >= Nn) return;
    const int b = batch[n];
    const int bp = (n == 0) ? -1 : batch[n - 1];
    for (int g = bp + 1; g <= b; ++g) gstart[g] = n;
    if (n == Nn - 1)
        for (int g = b + 1; g <= N_GRAPHS; ++g) gstart[g] = Nn;
}

__global__ __launch_bounds__(128) void pool_seg(const float* __restrict__ h,
                                                const int* __restrict__ gstart,
                                                float* __restrict__ hg)
{
    const int g = blockIdx.x;
    const int part = blockIdx.y;
    const int t = threadIdx.x;
    const int b0 = gstart[g], b1 = gstart[g + 1];
    float acc = 0.f;
    for (int n = b0 + part; n < b1; n += 4) acc += h[(size_t)n * H + t];
    atomicAdd(&hg[(size_t)g * H + t], acc);
}

__global__ __launch_bounds__(64) void mlp_kernel(
    const float* __restrict__ hg,
    const float* __restrict__ W4, const float* __restrict__ b4,
    const float* __restrict__ W5, const float* __restrict__ b5,
    float* __restrict__ out)
{
    const int g = blockIdx.x;
    const int c = threadIdx.x;
    __shared__ float hrow[H];
    for (int k = c; k < H; k += 64) hrow[k] = hg[(size_t)g * H + k];
    __syncthreads();
    float s = b4[c];
    #pragma unroll 8
    for (int k = 0; k < H; ++k) s += hrow[k] * W4[(size_t)k * 64 + c];
    s = fmaxf(s, 0.f) * W5[c];
    #pragma unroll
    for (int off = 32; off > 0; off >>= 1) s += __shfl_down(s, off);
    if (c == 0) out[g] = 1.f / (1.f + __expf(-(s + b5[0])));
}

// ---------------------------------------------------------------------------
extern "C" void kernel_launch(void* const* d_in, const int* in_sizes, int n_in,
                              void* d_out, int out_size, void* d_ws, size_t ws_size,
                              hipStream_t stream)
{
    const float* x = (const float*)d_in[0];
    const float *Wk[3], *bk[3], *Wq[3], *bq[3], *Wv[3], *bv[3], *Wsk[3], *bs[3];
    for (int l = 0; l < 3; ++l) {
        const int base = 2 + l * 8;
        Wk[l]  = (const float*)d_in[base + 0]; bk[l] = (const float*)d_in[base + 1];
        Wq[l]  = (const float*)d_in[base + 2]; bq[l] = (const float*)d_in[base + 3];
        Wv[l]  = (const float*)d_in[base + 4]; bv[l] = (const float*)d_in[base + 5];
        Wsk[l] = (const float*)d_in[base + 6]; bs[l] = (const float*)d_in[base + 7];
    }
    const float* W4 = (const float*)d_in[26];
    const float* b4 = (const float*)d_in[27];
    const float* W5 = (const float*)d_in[28];
    const float* b5 = (const float*)d_in[29];
    const int* ei    = (const int*)d_in[30];
    const int* batch = (const int*)d_in[31];
    float* out = (float*)d_out;

    const size_t NH = (size_t)N_NODES * H;
    const size_t AH = (size_t)MP * 128;
    const size_t WH = (size_t)3 * 512 * 128;
    float*     Kb   = (float*)d_ws;
    float*     hbuf = Kb + NH;
    _Float16*  Q16  = (_Float16*)(hbuf + NH);
    _Float16*  V16  = Q16 + NH;
    short*     Ahb  = (short*)(V16 + NH);
    short*     Alb  = Ahb + AH;
    short*     Wth  = Alb + AH;
    short*     Wtl  = Wth + WH;
    float*     hg   = (float*)(Wtl + WH);             // G*H  (zeroed)
    int*       off  = (int*)(hg + (size_t)N_GRAPHS * H);  // N+1 (zeroed, then overwritten)
    int*       cnt  = off + (N_NODES + 1);            // N   (zeroed)
    int*       csr  = cnt + N_NODES;                  // E
    int*       gst  = csr + N_EDGES;                  // G+1
    int*       bsum = gst + (N_GRAPHS + 1);           // 256
    int*       bsoff= bsum + 256;                     // 256
    const size_t need = (2 * NH + (size_t)N_GRAPHS * H) * sizeof(float)
                      + 2 * NH * sizeof(_Float16)
                      + (2 * AH + 2 * WH) * sizeof(short)
                      + (size_t)(2 * N_NODES + 1 + N_EDGES + N_GRAPHS + 1 + 512) * sizeof(int);
    if (ws_size < need) return;

    const int eblk = (N_EDGES + 255) / 256;
    const int ablk = (N_NODES + 3) / 4;
    const int nblk = (N_NODES + 255) / 256;
    const int cablk = (MP * 16) / 256;
    const dim3 ggrid(MP / 128, 4);
    const dim3 pgrid(N_GRAPHS, 4);

    // ---- one fused memset: hg (pool accum) + off + cnt (contiguous)
    hipMemsetAsync(hg, 0,
        ((size_t)N_GRAPHS * H + 2 * N_NODES + 1) * sizeof(int), stream);

    // ---- CSR + graph segments + weight conversion (reused across layers)
    hist_kernel<<<eblk, 256, 0, stream>>>(ei, cnt, N_EDGES);
    scan_p1<<<NB_SCAN, 256, 0, stream>>>(cnt, bsum, N_NODES);
    scan_p2<<<1, 256, 0, stream>>>(bsum, bsoff, off, N_NODES);
    scan_p3<<<NB_SCAN, 256, 0, stream>>>(cnt, bsoff, off, N_NODES);
    scatter_kernel<<<eblk, 256, 0, stream>>>(ei, cnt, csr, N_EDGES);
    gstart_kernel<<<nblk, 256, 0, stream>>>(batch, gst, N_NODES);
    conv_W<<<256, 256, 0, stream>>>(Wk[0], Wq[0], Wv[0], Wsk[0], DIN, Wth,               Wtl);
    conv_W<<<256, 256, 0, stream>>>(Wk[1], Wq[1], Wv[1], Wsk[1], H,   Wth + 512 * 128,  Wtl + 512 * 128);
    conv_W<<<256, 256, 0, stream>>>(Wk[2], Wq[2], Wv[2], Wsk[2], H,   Wth + 1024 * 128, Wtl + 1024 * 128);

    // ---- Layer 1
    conv_A<<<cablk, 256, 0, stream>>>(x, N_NODES, DIN, 0, Ahb, Alb);
    gemm_mfma<<<ggrid, 256, 0, stream>>>(Ahb, Alb, Wth, Wtl,
        bk[0], bq[0], bv[0], bs[0], Kb, Q16, V16, hbuf, N_NODES);
    agg_csr<<<ablk, 256, 0, stream>>>(Kb, Q16, V16, off, csr, hbuf, N_NODES);

    // ---- Layer 2
    conv_A<<<cablk, 256, 0, stream>>>(hbuf, N_NODES, H, 1, Ahb, Alb);
    gemm_mfma<<<ggrid, 256, 0, stream>>>(Ahb, Alb, Wth + 512 * 128, Wtl + 512 * 128,
        bk[1], bq[1], bv[1], bs[1], Kb, Q16, V16, hbuf, N_NODES);
    agg_csr<<<ablk, 256, 0, stream>>>(Kb, Q16, V16, off, csr, hbuf, N_NODES);

    // ---- Layer 3
    conv_A<<<cablk, 256, 0, stream>>>(hbuf, N_NODES, H, 1, Ahb, Alb);
    gemm_mfma<<<ggrid, 256, 0, stream>>>(Ahb, Alb, Wth + 1024 * 128, Wtl + 1024 * 128,
        bk[2], bq[2], bv[2], bs[2], Kb, Q16, V16, hbuf, N_NODES);
    agg_csr<<<ablk, 256, 0, stream>>>(Kb, Q16, V16, off, csr, hbuf, N_NODES);

    // ---- Pool + MLP
    pool_seg<<<pgrid, 128, 0, stream>>>(hbuf, gst, hg);
    mlp_kernel<<<N_GRAPHS, 64, 0, stream>>>(hg, W4, b4, W5, b5, out);
}

// Round 6
// 516.746 us; speedup vs baseline: 9.4021x; 1.1110x over previous
//
#include <hip/hip_runtime.h>

#define N_NODES 50000
#define N_EDGES 800000
#define N_GRAPHS 256
#define DIN 126
#define H 128
#define MP 50048           // N_NODES padded to 128
#define NB_SCAN 196        // ceil(N_NODES/256)

typedef __attribute__((ext_vector_type(8))) short short8v;
typedef __attribute__((ext_vector_type(8))) _Float16 half8v;
typedef __attribute__((ext_vector_type(4))) float f32x4;

// ---------------------------------------------------------------------------
// fp32 -> bf16 hi/lo split helpers (RNE)
// ---------------------------------------------------------------------------
__device__ __forceinline__ unsigned short f2bf(float f) {
    const unsigned u = __float_as_uint(f);
    return (unsigned short)((u + 0x7FFFu + ((u >> 16) & 1u)) >> 16);
}
__device__ __forceinline__ float bf2f(unsigned short s) {
    return __uint_as_float(((unsigned)s) << 16);
}
__device__ __forceinline__ float fast_sigmoid(float x) {
    // rcp-based: error ~2^-22, far below the fp16 Q/V error already accepted
    return __builtin_amdgcn_rcpf(1.f + __expf(-x));
}

// ---------------------------------------------------------------------------
// A conversion (layer-1 input only): X fp32 [M,Kd] -> Ah,Al bf16 [MP][128]
// Writes ALL MP rows (zeros past M/Kd) so pad rows are clean every call.
// ---------------------------------------------------------------------------
__global__ __launch_bounds__(256) void conv_A(const float* __restrict__ X, int M, int Kd,
                                              short* __restrict__ Ah,
                                              short* __restrict__ Al)
{
    const int t = blockIdx.x * 256 + threadIdx.x;
    const int row = t >> 4;
    if (row >= MP) return;
    const int k0 = (t & 15) * 8;
    short8v hv, lv;
    #pragma unroll
    for (int j = 0; j < 8; ++j) {
        const int k = k0 + j;
        float v = 0.f;
        if (row < M && k < Kd) v = X[(size_t)row * Kd + k];
        const unsigned short hb = f2bf(v);
        const float lo = v - bf2f(hb);
        hv[j] = (short)hb;
        lv[j] = (short)f2bf(lo);
    }
    const size_t o = (size_t)row * 128 + k0;
    *(short8v*)&Ah[o] = hv;
    *(short8v*)&Al[o] = lv;
}

// ---------------------------------------------------------------------------
// W conversion (one layer): four [Kd,128] fp32 -> transposed Wth/Wtl bf16
// ---------------------------------------------------------------------------
__global__ __launch_bounds__(256) void conv_W(
    const float* __restrict__ W0, const float* __restrict__ W1,
    const float* __restrict__ W2, const float* __restrict__ W3,
    int Kd, short* __restrict__ Wth, short* __restrict__ Wtl)
{
    const int t = blockIdx.x * 256 + threadIdx.x;
    if (t >= 512 * 128) return;
    const int n = t >> 7, k = t & 127;
    const int mtx = n >> 7, cc = n & 127;
    const float* W = mtx == 0 ? W0 : mtx == 1 ? W1 : mtx == 2 ? W2 : W3;
    const float v = (k < Kd) ? W[(size_t)k * 128 + cc] : 0.f;
    const unsigned short hb = f2bf(v);
    Wth[t] = (short)hb;
    Wtl[t] = (short)f2bf(v - bf2f(hb));
}

// ---------------------------------------------------------------------------
// MFMA GEMM (hi/lo split).  Outputs: K (fp32), Q (fp16), V (fp16), skip (fp32).
// ---------------------------------------------------------------------------
__global__ __launch_bounds__(256) void gemm_mfma(
    const short* __restrict__ Ah, const short* __restrict__ Al,
    const short* __restrict__ Wth, const short* __restrict__ Wtl,
    const float* __restrict__ bias0, const float* __restrict__ bias1,
    const float* __restrict__ bias2, const float* __restrict__ bias3,
    float* __restrict__ OK, _Float16* __restrict__ OQ,
    _Float16* __restrict__ OV, float* __restrict__ OS, int M)
{
    __shared__ short lds[4][8192];
    const int t = threadIdx.x;
    const int l = t & 63, w = t >> 6;
    const int wr = w >> 1, wc = w & 1;
    const int mtx = blockIdx.y;
    const int row0 = blockIdx.x * 128;
    const int ncol0 = mtx * 128;

    f32x4 acc[4][4] = {};

    for (int c = 0; c < 2; ++c) {
        __syncthreads();
        #pragma unroll
        for (int i = 0; i < 4; ++i) {
            const int li = i * 256 + t;
            const int r = li >> 3, k16 = li & 7;
            const int lo = r * 64 + ((k16 ^ (r & 7)) * 8);
            const size_t ga = (size_t)(row0 + r) * 128 + c * 64 + k16 * 8;
            const size_t gw = (size_t)(ncol0 + r) * 128 + c * 64 + k16 * 8;
            *(short8v*)&lds[0][lo] = *(const short8v*)&Ah[ga];
            *(short8v*)&lds[1][lo] = *(const short8v*)&Al[ga];
            *(short8v*)&lds[2][lo] = *(const short8v*)&Wth[gw];
            *(short8v*)&lds[3][lo] = *(const short8v*)&Wtl[gw];
        }
        __syncthreads();
        #pragma unroll
        for (int s = 0; s < 2; ++s) {
            short8v ah[4], al[4], wh[4], wl[4];
            const int kg = s * 4 + (l >> 4);
            #pragma unroll
            for (int m = 0; m < 4; ++m) {
                const int ar = wr * 64 + m * 16 + (l & 15);
                const int ao = ar * 64 + ((kg ^ (ar & 7)) * 8);
                ah[m] = *(const short8v*)&lds[0][ao];
                al[m] = *(const short8v*)&lds[1][ao];
                const int br = wc * 64 + m * 16 + (l & 15);
                const int bo = br * 64 + ((kg ^ (br & 7)) * 8);
                wh[m] = *(const short8v*)&lds[2][bo];
                wl[m] = *(const short8v*)&lds[3][bo];
            }
            #pragma unroll
            for (int m = 0; m < 4; ++m)
                #pragma unroll
                for (int n = 0; n < 4; ++n) {
                    acc[m][n] = __builtin_amdgcn_mfma_f32_16x16x32_bf16(ah[m], wh[n], acc[m][n], 0, 0, 0);
                    acc[m][n] = __builtin_amdgcn_mfma_f32_16x16x32_bf16(ah[m], wl[n], acc[m][n], 0, 0, 0);
                    acc[m][n] = __builtin_amdgcn_mfma_f32_16x16x32_bf16(al[m], wh[n], acc[m][n], 0, 0, 0);
                }
        }
    }

    const float* bias = mtx == 0 ? bias0 : mtx == 1 ? bias1 : mtx == 2 ? bias2 : bias3;
    if (mtx == 0 || mtx == 3) {
        float* O = (mtx == 0) ? OK : OS;
        #pragma unroll
        for (int n = 0; n < 4; ++n) {
            const int col = wc * 64 + n * 16 + (l & 15);
            const float bv = bias[col];
            #pragma unroll
            for (int m = 0; m < 4; ++m) {
                const int rb = row0 + wr * 64 + m * 16 + ((l >> 4) * 4);
                #pragma unroll
                for (int j = 0; j < 4; ++j) {
                    const int r = rb + j;
                    if (r < M) O[(size_t)r * 128 + col] = acc[m][n][j] + bv;
                }
            }
        }
    } else {
        _Float16* O = (mtx == 1) ? OQ : OV;
        #pragma unroll
        for (int n = 0; n < 4; ++n) {
            const int col = wc * 64 + n * 16 + (l & 15);
            const float bv = bias[col];
            #pragma unroll
            for (int m = 0; m < 4; ++m) {
                const int rb = row0 + wr * 64 + m * 16 + ((l >> 4) * 4);
                #pragma unroll
                for (int j = 0; j < 4; ++j) {
                    const int r = rb + j;
                    if (r < M) O[(size_t)r * 128 + col] = (_Float16)(acc[m][n][j] + bv);
                }
            }
        }
    }
}

// ---------------------------------------------------------------------------
// CSR build (unchanged from R5)
// ---------------------------------------------------------------------------
__global__ __launch_bounds__(256) void hist_kernel(const int* __restrict__ ei,
                                                   int* __restrict__ cnt, int E)
{
    const int e = blockIdx.x * 256 + threadIdx.x;
    if (e < E) atomicAdd(&cnt[ei[E + e]], 1);
}

__global__ __launch_bounds__(256) void scan_p1(const int* __restrict__ cnt,
                                               int* __restrict__ bsum, int Nn)
{
    __shared__ int red[256];
    const int t = threadIdx.x;
    const int i = blockIdx.x * 256 + t;
    red[t] = (i < Nn) ? cnt[i] : 0;
    __syncthreads();
    for (int d = 128; d > 0; d >>= 1) {
        if (t < d) red[t] += red[t + d];
        __syncthreads();
    }
    if (t == 0) bsum[blockIdx.x] = red[0];
}

__global__ __launch_bounds__(256) void scan_p2(const int* __restrict__ bsum,
                                               int* __restrict__ bsoff,
                                               int* __restrict__ off, int Nn)
{
    __shared__ int sc[256];
    const int t = threadIdx.x;
    const int v = (t < NB_SCAN) ? bsum[t] : 0;
    sc[t] = v;
    __syncthreads();
    #pragma unroll
    for (int d = 1; d < 256; d <<= 1) {
        const int a = (t >= d) ? sc[t - d] : 0;
        __syncthreads();
        sc[t] += a;
        __syncthreads();
    }
    if (t < NB_SCAN) bsoff[t] = sc[t] - v;
    if (t == NB_SCAN - 1) off[Nn] = sc[t];
}

__global__ __launch_bounds__(256) void scan_p3(int* __restrict__ cnt,
                                               const int* __restrict__ bsoff,
                                               int* __restrict__ off, int Nn)
{
    __shared__ int sc[256];
    const int t = threadIdx.x;
    const int i = blockIdx.x * 256 + t;
    const int v = (i < Nn) ? cnt[i] : 0;
    sc[t] = v;
    __syncthreads();
    #pragma unroll
    for (int d = 1; d < 256; d <<= 1) {
        const int a = (t >= d) ? sc[t - d] : 0;
        __syncthreads();
        sc[t] += a;
        __syncthreads();
    }
    if (i < Nn) {
        const int o = bsoff[blockIdx.x] + sc[t] - v;
        off[i] = o;
        cnt[i] = o;
    }
}

__global__ __launch_bounds__(256) void scatter_kernel(const int* __restrict__ ei,
                                                      int* __restrict__ cur,
                                                      int* __restrict__ csr_src, int E)
{
    const int e = blockIdx.x * 256 + threadIdx.x;
    if (e >= E) return;
    const int s = ei[e];
    const int d = ei[E + e];
    const int pos = atomicAdd(&cur[d], 1);
    csr_src[pos] = s;
}

// ---------------------------------------------------------------------------
// CSR aggregation v4: fp16 Q/V gathers, 16 lanes/edge, rcp-sigmoid.
// FUSE=1 (layers 1-2): epilogue = skip + agg, relu, bf16 hi/lo split ->
// writes Ah/Al (next layer's GEMM input), no fp32 h write.
// FUSE=0 (layer 3): writes fp32 h into hSkip (for the pool).
// ---------------------------------------------------------------------------
template<int FUSE>
__global__ __launch_bounds__(256) void agg_csr(
    const float* __restrict__ Kb, const _Float16* __restrict__ Q16,
    const _Float16* __restrict__ V16, const int* __restrict__ off,
    const int* __restrict__ csr_src, float* __restrict__ hSkip,
    short* __restrict__ Ah, short* __restrict__ Al, int Nn)
{
    const int node = blockIdx.x * 4 + (threadIdx.x >> 6);
    if (node >= Nn) return;
    const int lane = threadIdx.x & 63;
    const int grp = lane >> 4;           // 0..3: which edge of the quad
    const int sub = lane & 15;           // 16 lanes x 8 dims = 128
    const int q = sub * 8;

    const float4 kA = *(const float4*)(Kb + (size_t)node * H + q);
    const float4 kB = *(const float4*)(Kb + (size_t)node * H + q + 4);
    float acc[8] = {};

    const int begin = off[node], end = off[node + 1];
    for (int j0 = begin; j0 < end; j0 += 64) {
        const int nrem = end - j0;
        const int nk = nrem < 64 ? nrem : 64;
        const int sv = (lane < nk) ? csr_src[j0 + lane] : 0;
        #pragma unroll 2
        for (int k = 0; k < nk; k += 4) {
            const int myk = k + grp;
            const int s = __shfl(sv, myk < nk ? myk : 0);
            if (myk < nk) {
                const half8v qv = *(const half8v*)(Q16 + (size_t)s * H + q);
                const half8v vv = *(const half8v*)(V16 + (size_t)s * H + q);
                acc[0] = fmaf((float)vv[0], fast_sigmoid(kA.x + (float)qv[0]), acc[0]);
                acc[1] = fmaf((float)vv[1], fast_sigmoid(kA.y + (float)qv[1]), acc[1]);
                acc[2] = fmaf((float)vv[2], fast_sigmoid(kA.z + (float)qv[2]), acc[2]);
                acc[3] = fmaf((float)vv[3], fast_sigmoid(kA.w + (float)qv[3]), acc[3]);
                acc[4] = fmaf((float)vv[4], fast_sigmoid(kB.x + (float)qv[4]), acc[4]);
                acc[5] = fmaf((float)vv[5], fast_sigmoid(kB.y + (float)qv[5]), acc[5]);
                acc[6] = fmaf((float)vv[6], fast_sigmoid(kB.z + (float)qv[6]), acc[6]);
                acc[7] = fmaf((float)vv[7], fast_sigmoid(kB.w + (float)qv[7]), acc[7]);
            }
        }
    }
    // sum the 4 edge-groups (butterfly over lane bits 4,5)
    #pragma unroll
    for (int i = 0; i < 8; ++i) {
        acc[i] += __shfl_xor(acc[i], 16);
        acc[i] += __shfl_xor(acc[i], 32);
    }
    if (grp == 0) {
        const float* sk = hSkip + (size_t)node * H + q;
        const float4 eA = *(const float4*)sk;
        const float4 eB = *(const float4*)(sk + 4);
        float h[8];
        h[0] = eA.x + acc[0]; h[1] = eA.y + acc[1];
        h[2] = eA.z + acc[2]; h[3] = eA.w + acc[3];
        h[4] = eB.x + acc[4]; h[5] = eB.y + acc[5];
        h[6] = eB.z + acc[6]; h[7] = eB.w + acc[7];
        if (FUSE) {
            short8v hv, lv;
            #pragma unroll
            for (int j = 0; j < 8; ++j) {
                const float v = fmaxf(h[j], 0.f);
                const unsigned short hb = f2bf(v);
                hv[j] = (short)hb;
                lv[j] = (short)f2bf(v - bf2f(hb));
            }
            const size_t o = (size_t)node * 128 + q;
            *(short8v*)&Ah[o] = hv;
            *(short8v*)&Al[o] = lv;
        } else {
            float* o = hSkip + (size_t)node * H + q;
            *(float4*)o = make_float4(h[0], h[1], h[2], h[3]);
            *(float4*)(o + 4) = make_float4(h[4], h[5], h[6], h[7]);
        }
    }
}

// ---------------------------------------------------------------------------
// Pool + MLP (unchanged)
// ---------------------------------------------------------------------------
__global__ __launch_bounds__(256) void gstart_kernel(const int* __restrict__ batch,
                                                     int* __restrict__ gstart, int Nn)
{
    const int n = blockIdx.x * 256 + threadIdx.x;
    if (n >= Nn) return;
    const int b = batch[n];
    const int bp = (n == 0) ? -1 : batch[n - 1];
    for (int g = bp + 1; g <= b; ++g) gstart[g] = n;
    if (n == Nn - 1)
        for (int g = b + 1; g <= N_GRAPHS; ++g) gstart[g] = Nn;
}

__global__ __launch_bounds__(128) void pool_seg(const float* __restrict__ h,
                                                const int* __restrict__ gstart,
                                                float* __restrict__ hg)
{
    const int g = blockIdx.x;
    const int part = blockIdx.y;
    const int t = threadIdx.x;
    const int b0 = gstart[g], b1 = gstart[g + 1];
    float acc = 0.f;
    for (int n = b0 + part; n < b1; n += 4) acc += h[(size_t)n * H + t];
    atomicAdd(&hg[(size_t)g * H + t], acc);
}

__global__ __launch_bounds__(64) void mlp_kernel(
    const float* __restrict__ hg,
    const float* __restrict__ W4, const float* __restrict__ b4,
    const float* __restrict__ W5, const float* __restrict__ b5,
    float* __restrict__ out)
{
    const int g = blockIdx.x;
    const int c = threadIdx.x;
    __shared__ float hrow[H];
    for (int k = c; k < H; k += 64) hrow[k] = hg[(size_t)g * H + k];
    __syncthreads();
    float s = b4[c];
    #pragma unroll 8
    for (int k = 0; k < H; ++k) s += hrow[k] * W4[(size_t)k * 64 + c];
    s = fmaxf(s, 0.f) * W5[c];
    #pragma unroll
    for (int off = 32; off > 0; off >>= 1) s += __shfl_down(s, off);
    if (c == 0) out[g] = 1.f / (1.f + __expf(-(s + b5[0])));
}

// ---------------------------------------------------------------------------
extern "C" void kernel_launch(void* const* d_in, const int* in_sizes, int n_in,
                              void* d_out, int out_size, void* d_ws, size_t ws_size,
                              hipStream_t stream)
{
    const float* x = (const float*)d_in[0];
    const float *Wk[3], *bk[3], *Wq[3], *bq[3], *Wv[3], *bv[3], *Wsk[3], *bs[3];
    for (int l = 0; l < 3; ++l) {
        const int base = 2 + l * 8;
        Wk[l]  = (const float*)d_in[base + 0]; bk[l] = (const float*)d_in[base + 1];
        Wq[l]  = (const float*)d_in[base + 2]; bq[l] = (const float*)d_in[base + 3];
        Wv[l]  = (const float*)d_in[base + 4]; bv[l] = (const float*)d_in[base + 5];
        Wsk[l] = (const float*)d_in[base + 6]; bs[l] = (const float*)d_in[base + 7];
    }
    const float* W4 = (const float*)d_in[26];
    const float* b4 = (const float*)d_in[27];
    const float* W5 = (const float*)d_in[28];
    const float* b5 = (const float*)d_in[29];
    const int* ei    = (const int*)d_in[30];
    const int* batch = (const int*)d_in[31];
    float* out = (float*)d_out;

    const size_t NH = (size_t)N_NODES * H;
    const size_t AH = (size_t)MP * 128;
    const size_t WH = (size_t)3 * 512 * 128;
    float*     Kb   = (float*)d_ws;
    float*     hbuf = Kb + NH;
    _Float16*  Q16  = (_Float16*)(hbuf + NH);
    _Float16*  V16  = Q16 + NH;
    short*     Ahb  = (short*)(V16 + NH);
    short*     Alb  = Ahb + AH;
    short*     Wth  = Alb + AH;
    short*     Wtl  = Wth + WH;
    float*     hg   = (float*)(Wtl + WH);                 // G*H (zeroed)
    int*       off  = (int*)(hg + (size_t)N_GRAPHS * H);  // N+1 (zeroed)
    int*       cnt  = off + (N_NODES + 1);                // N   (zeroed)
    int*       csr  = cnt + N_NODES;                      // E
    int*       gst  = csr + N_EDGES;                      // G+1
    int*       bsum = gst + (N_GRAPHS + 1);               // 256
    int*       bsoff= bsum + 256;                         // 256
    const size_t need = (2 * NH + (size_t)N_GRAPHS * H) * sizeof(float)
                      + 2 * NH * sizeof(_Float16)
                      + (2 * AH + 2 * WH) * sizeof(short)
                      + (size_t)(2 * N_NODES + 1 + N_EDGES + N_GRAPHS + 1 + 512) * sizeof(int);
    if (ws_size < need) return;

    const int eblk = (N_EDGES + 255) / 256;
    const int ablk = (N_NODES + 3) / 4;
    const int nblk = (N_NODES + 255) / 256;
    const int cablk = (MP * 16) / 256;
    const dim3 ggrid(MP / 128, 4);
    const dim3 pgrid(N_GRAPHS, 4);

    // ---- one fused memset: hg (pool accum) + off + cnt (contiguous)
    hipMemsetAsync(hg, 0,
        ((size_t)N_GRAPHS * H + 2 * N_NODES + 1) * sizeof(int), stream);

    // ---- CSR + graph segments + weight conversion (reused across layers)
    hist_kernel<<<eblk, 256, 0, stream>>>(ei, cnt, N_EDGES);
    scan_p1<<<NB_SCAN, 256, 0, stream>>>(cnt, bsum, N_NODES);
    scan_p2<<<1, 256, 0, stream>>>(bsum, bsoff, off, N_NODES);
    scan_p3<<<NB_SCAN, 256, 0, stream>>>(cnt, bsoff, off, N_NODES);
    scatter_kernel<<<eblk, 256, 0, stream>>>(ei, cnt, csr, N_EDGES);
    gstart_kernel<<<nblk, 256, 0, stream>>>(batch, gst, N_NODES);
    conv_W<<<256, 256, 0, stream>>>(Wk[0], Wq[0], Wv[0], Wsk[0], DIN, Wth,               Wtl);
    conv_W<<<256, 256, 0, stream>>>(Wk[1], Wq[1], Wv[1], Wsk[1], H,   Wth + 512 * 128,  Wtl + 512 * 128);
    conv_W<<<256, 256, 0, stream>>>(Wk[2], Wq[2], Wv[2], Wsk[2], H,   Wth + 1024 * 128, Wtl + 1024 * 128);

    // ---- Layer 1 (conv_A writes all MP rows incl. zero pads, reused by L2/L3)
    conv_A<<<cablk, 256, 0, stream>>>(x, N_NODES, DIN, Ahb, Alb);
    gemm_mfma<<<ggrid, 256, 0, stream>>>(Ahb, Alb, Wth, Wtl,
        bk[0], bq[0], bv[0], bs[0], Kb, Q16, V16, hbuf, N_NODES);
    agg_csr<1><<<ablk, 256, 0, stream>>>(Kb, Q16, V16, off, csr, hbuf, Ahb, Alb, N_NODES);

    // ---- Layer 2 (reads Ah/Al written by L1's agg)
    gemm_mfma<<<ggrid, 256, 0, stream>>>(Ahb, Alb, Wth + 512 * 128, Wtl + 512 * 128,
        bk[1], bq[1], bv[1], bs[1], Kb, Q16, V16, hbuf, N_NODES);
    agg_csr<1><<<ablk, 256, 0, stream>>>(Kb, Q16, V16, off, csr, hbuf, Ahb, Alb, N_NODES);

    // ---- Layer 3 (final: fp32 h into hbuf for the pool)
    gemm_mfma<<<ggrid, 256, 0, stream>>>(Ahb, Alb, Wth + 1024 * 128, Wtl + 1024 * 128,
        bk[2], bq[2], bv[2], bs[2], Kb, Q16, V16, hbuf, N_NODES);
    agg_csr<0><<<ablk, 256, 0, stream>>>(Kb, Q16, V16, off, csr, hbuf, Ahb, Alb, N_NODES);

    // ---- Pool + MLP
    pool_seg<<<pgrid, 128, 0, stream>>>(hbuf, gst, hg);
    mlp_kernel<<<N_GRAPHS, 64, 0, stream>>>(hg, W4, b4, W5, b5, out);
}